// Round 1
// baseline (2927.107 us; speedup 1.0000x reference)
//
#include <hip/hip_runtime.h>
#include <hip/hip_bf16.h>
#include <math.h>

#define NN 8192
#define DD 256
#define HH 128
#define RPB 16
#define DT_F 0.01f
#define TWO_PI_F 6.28318530717958647692f

__device__ __forceinline__ float gelu_exact(float t) {
    return 0.5f * t * (1.f + erff(t * 0.70710678118654752440f));
}
__device__ __forceinline__ float sigmoidf(float t) {
    return 1.f / (1.f + expf(-t));
}

// ---------------- pre: frequencies, coupling, phases0, cos/sin snapshot ----
__global__ __launch_bounds__(256) void pre_kernel(
    const float* __restrict__ x,
    const float* __restrict__ fw1, const float* __restrict__ fb1,
    const float* __restrict__ flng, const float* __restrict__ flnb,
    const float* __restrict__ fw2, const float* __restrict__ fb2,
    const float* __restrict__ fw3, const float* __restrict__ fb3,
    const float* __restrict__ cw1, const float* __restrict__ cb1,
    const float* __restrict__ cw2, const float* __restrict__ cb2,
    const float* __restrict__ gcp,
    float* __restrict__ freq_out, float* __restrict__ coup_out,
    float* __restrict__ cs_ws, float* __restrict__ phases_out,
    float* __restrict__ pc0, float* __restrict__ ps0)
{
    __shared__ float xs[RPB][DD];
    __shared__ float h1[RPB][DD];
    __shared__ float h2[RPB][HH];
    __shared__ float hc[RPB][HH];
    const int tid = threadIdx.x;
    const int base_row = blockIdx.x * RPB;

    // load x tile
    {
        const float4* xg = (const float4*)(x + (size_t)base_row * DD);
        float4* xv = (float4*)&xs[0][0];
        for (int i = tid; i < RPB * DD / 4; i += 256) xv[i] = xg[i];
    }
    __syncthreads();

    // h1 = x @ fw1 + fb1
    {
        float acc[RPB];
#pragma unroll
        for (int r = 0; r < RPB; ++r) acc[r] = 0.f;
        const int c = tid;
        for (int k = 0; k < DD; k += 4) {
            float w0 = fw1[(k + 0) * DD + c];
            float w1 = fw1[(k + 1) * DD + c];
            float w2 = fw1[(k + 2) * DD + c];
            float w3 = fw1[(k + 3) * DD + c];
#pragma unroll
            for (int r = 0; r < RPB; ++r) {
                float4 xv = *(const float4*)&xs[r][k];
                acc[r] += xv.x * w0 + xv.y * w1 + xv.z * w2 + xv.w * w3;
            }
        }
        float bb = fb1[c];
#pragma unroll
        for (int r = 0; r < RPB; ++r) h1[r][c] = acc[r] + bb;
    }
    __syncthreads();

    // LN + tanh per row (one wave per row)
    {
        const int wave = tid >> 6, lane = tid & 63;
        for (int r = wave; r < RPB; r += 4) {
            float v0 = h1[r][lane], v1 = h1[r][lane + 64], v2 = h1[r][lane + 128], v3 = h1[r][lane + 192];
            float s = v0 + v1 + v2 + v3;
            for (int off = 32; off; off >>= 1) s += __shfl_xor(s, off);
            float m = s * (1.f / DD);
            float d0 = v0 - m, d1 = v1 - m, d2 = v2 - m, d3 = v3 - m;
            float q = d0 * d0 + d1 * d1 + d2 * d2 + d3 * d3;
            for (int off = 32; off; off >>= 1) q += __shfl_xor(q, off);
            float rstd = rsqrtf(q * (1.f / DD) + 1e-5f);
            h1[r][lane]       = tanhf(d0 * rstd * flng[lane]       + flnb[lane]);
            h1[r][lane + 64]  = tanhf(d1 * rstd * flng[lane + 64]  + flnb[lane + 64]);
            h1[r][lane + 128] = tanhf(d2 * rstd * flng[lane + 128] + flnb[lane + 128]);
            h1[r][lane + 192] = tanhf(d3 * rstd * flng[lane + 192] + flnb[lane + 192]);
        }
    }
    __syncthreads();

    // h2 = tanh(h1 @ fw2 + fb2)  [threads 0..127] ; hc = gelu(x @ cw1 + cb1) [threads 128..255]
    if (tid < HH) {
        const int c = tid;
        float acc[RPB];
#pragma unroll
        for (int r = 0; r < RPB; ++r) acc[r] = 0.f;
        for (int k = 0; k < DD; k += 4) {
            float w0 = fw2[(k + 0) * HH + c];
            float w1 = fw2[(k + 1) * HH + c];
            float w2 = fw2[(k + 2) * HH + c];
            float w3 = fw2[(k + 3) * HH + c];
#pragma unroll
            for (int r = 0; r < RPB; ++r) {
                float4 xv = *(const float4*)&h1[r][k];
                acc[r] += xv.x * w0 + xv.y * w1 + xv.z * w2 + xv.w * w3;
            }
        }
        float bb = fb2[c];
#pragma unroll
        for (int r = 0; r < RPB; ++r) h2[r][c] = tanhf(acc[r] + bb);
    } else {
        const int c = tid - HH;
        float acc[RPB];
#pragma unroll
        for (int r = 0; r < RPB; ++r) acc[r] = 0.f;
        for (int k = 0; k < DD; k += 4) {
            float w0 = cw1[(k + 0) * HH + c];
            float w1 = cw1[(k + 1) * HH + c];
            float w2 = cw1[(k + 2) * HH + c];
            float w3 = cw1[(k + 3) * HH + c];
#pragma unroll
            for (int r = 0; r < RPB; ++r) {
                float4 xv = *(const float4*)&xs[r][k];
                acc[r] += xv.x * w0 + xv.y * w1 + xv.z * w2 + xv.w * w3;
            }
        }
        float bb = cb1[c];
#pragma unroll
        for (int r = 0; r < RPB; ++r) {
            float t = acc[r] + bb;
            hc[r][c] = gelu_exact(t);
        }
    }
    __syncthreads();

    // freq / coupling / phases0 : one wave per row
    {
        const int wave = tid >> 6, lane = tid & 63;
        float gc = fminf(fmaxf(gcp[0], 0.1f), 2.0f);
        for (int r = wave; r < RPB; r += 4) {
            float f = h2[r][lane] * fw3[lane] + h2[r][lane + 64] * fw3[lane + 64];
            for (int off = 32; off; off >>= 1) f += __shfl_xor(f, off);
            float cpl = hc[r][lane] * cw2[lane] + hc[r][lane + 64] * cw2[lane + 64];
            for (int off = 32; off; off >>= 1) cpl += __shfl_xor(cpl, off);
            float ssum = 0.f, csum = 0.f;
#pragma unroll
            for (int j = 0; j < 4; ++j) {
                int idx = lane + 64 * j;
                float xv = xs[r][idx];
                float fi = (float)idx;
                ssum += xv * sinf(fi);
                csum += xv * cosf(fi);
            }
            for (int off = 32; off; off >>= 1) {
                ssum += __shfl_xor(ssum, off);
                csum += __shfl_xor(csum, off);
            }
            if (lane == 0) {
                int row = base_row + r;
                freq_out[row] = f + fb3[0];
                float sg = sigmoidf(cpl + cb2[0]);
                coup_out[row] = sg;
                cs_ws[row] = sg * gc;
                float ph = atan2f(ssum, csum);
                phases_out[row] = ph;
                pc0[row] = cosf(ph);
                ps0[row] = sinf(ph);
            }
        }
    }
}

// ---------------- one Kuramoto step: fused matvec + phase update ------------
#define SROWS 8      // rows per block
#define CHUNK 4096   // column chunk staged in LDS
__global__ __launch_bounds__(256) void step_kernel(
    const float* __restrict__ A,
    const float* __restrict__ pc_in, const float* __restrict__ ps_in,
    const float* __restrict__ freq, const float* __restrict__ cs,
    float* __restrict__ phases,
    float* __restrict__ pc_out, float* __restrict__ ps_out)
{
    __shared__ float pcs[CHUNK];
    __shared__ float pss[CHUNK];
    const int tid = threadIdx.x, lane = tid & 63, wave = tid >> 6;
    const int row0 = blockIdx.x * SROWS + wave * (SROWS / 4);
    float accC[SROWS / 4], accS[SROWS / 4];
#pragma unroll
    for (int rr = 0; rr < SROWS / 4; ++rr) { accC[rr] = 0.f; accS[rr] = 0.f; }

    for (int ch = 0; ch < NN / CHUNK; ++ch) {
        const float4* pcg = (const float4*)(pc_in + ch * CHUNK);
        const float4* psg = (const float4*)(ps_in + ch * CHUNK);
        for (int i = tid; i < CHUNK / 4; i += 256) {
            ((float4*)pcs)[i] = pcg[i];
            ((float4*)pss)[i] = psg[i];
        }
        __syncthreads();
#pragma unroll
        for (int rr = 0; rr < SROWS / 4; ++rr) {
            const float4* Ar = (const float4*)(A + (size_t)(row0 + rr) * NN + ch * CHUNK);
            float lac = 0.f, las = 0.f;
#pragma unroll 4
            for (int it = 0; it < CHUNK / 256; ++it) {
                int c4 = it * 64 + lane;
                float4 a = Ar[c4];
                float4 c = ((const float4*)pcs)[c4];
                float4 s = ((const float4*)pss)[c4];
                lac += a.x * c.x + a.y * c.y + a.z * c.z + a.w * c.w;
                las += a.x * s.x + a.y * s.y + a.z * s.z + a.w * s.w;
            }
            accC[rr] += lac;
            accS[rr] += las;
        }
        __syncthreads();
    }

#pragma unroll
    for (int rr = 0; rr < SROWS / 4; ++rr) {
        float c = accC[rr], s = accS[rr];
        for (int off = 32; off; off >>= 1) {
            c += __shfl_xor(c, off);
            s += __shfl_xor(s, off);
        }
        if (lane == 0) {
            int row = row0 + rr;
            float ph = phases[row];
            float ce = atan2f(s, c + 1e-8f) - ph;
            float dphi = freq[row] + cs[row] * sinf(ce);
            float pn = ph + DT_F * dphi;
            pn = fmodf(pn, TWO_PI_F);
            if (pn < 0.f) pn += TWO_PI_F;
            phases[row] = pn;
            pc_out[row] = cosf(pn);
            ps_out[row] = sinf(pn);
        }
    }
}

// ---------------- post: sync_input, sync MLP -> desync ----------------------
#define SD 260
#define SDP 264
__global__ __launch_bounds__(256) void post_kernel(
    const float* __restrict__ x, const float* __restrict__ phases,
    const float* __restrict__ sw1, const float* __restrict__ sb1,
    const float* __restrict__ slng, const float* __restrict__ slnb,
    const float* __restrict__ sw2, const float* __restrict__ sb2,
    const float* __restrict__ sw3, const float* __restrict__ sb3,
    float* __restrict__ sync_out, float* __restrict__ desync_out)
{
    __shared__ float xs[RPB][SDP];
    __shared__ float h1[RPB][DD];
    __shared__ float h2[RPB][HH];
    const int tid = threadIdx.x;
    const int base_row = blockIdx.x * RPB;

    // load x tile
    for (int i = tid; i < RPB * DD / 4; i += 256) {
        int r = i / (DD / 4), c4 = i % (DD / 4);
        *(float4*)&xs[r][c4 * 4] = ((const float4*)(x + (size_t)(base_row + r) * DD))[c4];
    }
    if (tid < RPB) {
        float p = phases[base_row + tid];
        xs[tid][256] = cosf(p);
        xs[tid][257] = sinf(p);
        xs[tid][258] = cosf(2.f * p);
        xs[tid][259] = sinf(2.f * p);
    }
    __syncthreads();

    // write sync_input (scalar stores; base offset is not 16B aligned)
    for (int i = tid; i < RPB * SD; i += 256) {
        int r = i / SD, c = i % SD;
        sync_out[(size_t)(base_row + r) * SD + c] = xs[r][c];
    }

    // h1 = sync_input @ sw1 + sb1
    {
        float acc[RPB];
#pragma unroll
        for (int r = 0; r < RPB; ++r) acc[r] = 0.f;
        const int c = tid;
        for (int k = 0; k < SD; k += 4) {
            float w0 = sw1[(k + 0) * DD + c];
            float w1 = sw1[(k + 1) * DD + c];
            float w2 = sw1[(k + 2) * DD + c];
            float w3 = sw1[(k + 3) * DD + c];
#pragma unroll
            for (int r = 0; r < RPB; ++r) {
                float4 xv = *(const float4*)&xs[r][k];
                acc[r] += xv.x * w0 + xv.y * w1 + xv.z * w2 + xv.w * w3;
            }
        }
        float bb = sb1[c];
#pragma unroll
        for (int r = 0; r < RPB; ++r) h1[r][c] = acc[r] + bb;
    }
    __syncthreads();

    // LN + GELU per row
    {
        const int wave = tid >> 6, lane = tid & 63;
        for (int r = wave; r < RPB; r += 4) {
            float v0 = h1[r][lane], v1 = h1[r][lane + 64], v2 = h1[r][lane + 128], v3 = h1[r][lane + 192];
            float s = v0 + v1 + v2 + v3;
            for (int off = 32; off; off >>= 1) s += __shfl_xor(s, off);
            float m = s * (1.f / DD);
            float d0 = v0 - m, d1 = v1 - m, d2 = v2 - m, d3 = v3 - m;
            float q = d0 * d0 + d1 * d1 + d2 * d2 + d3 * d3;
            for (int off = 32; off; off >>= 1) q += __shfl_xor(q, off);
            float rstd = rsqrtf(q * (1.f / DD) + 1e-5f);
            h1[r][lane]       = gelu_exact(d0 * rstd * slng[lane]       + slnb[lane]);
            h1[r][lane + 64]  = gelu_exact(d1 * rstd * slng[lane + 64]  + slnb[lane + 64]);
            h1[r][lane + 128] = gelu_exact(d2 * rstd * slng[lane + 128] + slnb[lane + 128]);
            h1[r][lane + 192] = gelu_exact(d3 * rstd * slng[lane + 192] + slnb[lane + 192]);
        }
    }
    __syncthreads();

    // h2 = gelu(h1 @ sw2 + sb2)  [threads 0..127]
    if (tid < HH) {
        const int c = tid;
        float acc[RPB];
#pragma unroll
        for (int r = 0; r < RPB; ++r) acc[r] = 0.f;
        for (int k = 0; k < DD; k += 4) {
            float w0 = sw2[(k + 0) * HH + c];
            float w1 = sw2[(k + 1) * HH + c];
            float w2 = sw2[(k + 2) * HH + c];
            float w3 = sw2[(k + 3) * HH + c];
#pragma unroll
            for (int r = 0; r < RPB; ++r) {
                float4 xv = *(const float4*)&h1[r][k];
                acc[r] += xv.x * w0 + xv.y * w1 + xv.z * w2 + xv.w * w3;
            }
        }
        float bb = sb2[c];
#pragma unroll
        for (int r = 0; r < RPB; ++r) h2[r][c] = gelu_exact(acc[r] + bb);
    }
    __syncthreads();

    // desync = sigmoid(h2 @ sw3 + sb3) : one wave per row
    {
        const int wave = tid >> 6, lane = tid & 63;
        for (int r = wave; r < RPB; r += 4) {
            float t = h2[r][lane] * sw3[lane] + h2[r][lane + 64] * sw3[lane + 64];
            for (int off = 32; off; off >>= 1) t += __shfl_xor(t, off);
            if (lane == 0) desync_out[base_row + r] = sigmoidf(t + sb3[0]);
        }
    }
}

// ---------------- global scalar reductions ---------------------------------
__global__ __launch_bounds__(1024) void reduce_kernel(
    const float* __restrict__ phases,
    float* __restrict__ order_out, float* __restrict__ coh_out)
{
    __shared__ double red[16][4];
    const int tid = threadIdx.x;
    double sc = 0, ss = 0, sp = 0, spp = 0;
    for (int i = tid; i < NN; i += 1024) {
        float p = phases[i];
        sc += (double)cosf(p);
        ss += (double)sinf(p);
        sp += (double)p;
        spp += (double)p * (double)p;
    }
    const int lane = tid & 63, wave = tid >> 6;
    for (int off = 32; off; off >>= 1) {
        sc += __shfl_xor(sc, off);
        ss += __shfl_xor(ss, off);
        sp += __shfl_xor(sp, off);
        spp += __shfl_xor(spp, off);
    }
    if (lane == 0) { red[wave][0] = sc; red[wave][1] = ss; red[wave][2] = sp; red[wave][3] = spp; }
    __syncthreads();
    if (tid == 0) {
        sc = 0; ss = 0; sp = 0; spp = 0;
        for (int w = 0; w < 16; ++w) { sc += red[w][0]; ss += red[w][1]; sp += red[w][2]; spp += red[w][3]; }
        double mc = sc / NN, ms = ss / NN;
        order_out[0] = (float)sqrt(mc * mc + ms * ms);
        double var = (spp - sp * sp / NN) / (NN - 1);
        if (var < 0) var = 0;
        coh_out[0] = (float)(1.0 / (1.0 + sqrt(var)));
    }
}

extern "C" void kernel_launch(void* const* d_in, const int* in_sizes, int n_in,
                              void* d_out, int out_size, void* d_ws, size_t ws_size,
                              hipStream_t stream) {
    const float* x    = (const float*)d_in[0];
    const float* A    = (const float*)d_in[1];
    const float* fw1  = (const float*)d_in[2];
    const float* fb1  = (const float*)d_in[3];
    const float* flng = (const float*)d_in[4];
    const float* flnb = (const float*)d_in[5];
    const float* fw2  = (const float*)d_in[6];
    const float* fb2  = (const float*)d_in[7];
    const float* fw3  = (const float*)d_in[8];
    const float* fb3  = (const float*)d_in[9];
    const float* cw1  = (const float*)d_in[10];
    const float* cb1  = (const float*)d_in[11];
    const float* cw2  = (const float*)d_in[12];
    const float* cb2  = (const float*)d_in[13];
    const float* sw1  = (const float*)d_in[14];
    const float* sb1  = (const float*)d_in[15];
    const float* slng = (const float*)d_in[16];
    const float* slnb = (const float*)d_in[17];
    const float* sw2  = (const float*)d_in[18];
    const float* sb2  = (const float*)d_in[19];
    const float* sw3  = (const float*)d_in[20];
    const float* sb3  = (const float*)d_in[21];
    const float* gcp  = (const float*)d_in[22];

    float* out    = (float*)d_out;
    float* desync = out;                    // 8192
    float* order  = out + 8192;             // 1
    float* phases = out + 8193;             // 8192
    float* freqo  = out + 16385;            // 8192
    float* coupo  = out + 24577;            // 8192
    float* synco  = out + 32769;            // 8192*260
    float* coh    = out + 2162689;          // 1

    float* ws  = (float*)d_ws;
    float* pcA = ws;
    float* psA = ws + 8192;
    float* pcB = ws + 16384;
    float* psB = ws + 24576;
    float* cs  = ws + 32768;

    pre_kernel<<<NN / RPB, 256, 0, stream>>>(x, fw1, fb1, flng, flnb, fw2, fb2, fw3, fb3,
                                             cw1, cb1, cw2, cb2, gcp,
                                             freqo, coupo, cs, phases, pcA, psA);
    for (int t = 0; t < 60; ++t) {
        const float* pin = (t & 1) ? pcB : pcA;
        const float* sin_ = (t & 1) ? psB : psA;
        float* pout = (t & 1) ? pcA : pcB;
        float* sout = (t & 1) ? psA : psB;
        step_kernel<<<NN / SROWS, 256, 0, stream>>>(A, pin, sin_, freqo, cs, phases, pout, sout);
    }
    post_kernel<<<NN / RPB, 256, 0, stream>>>(x, phases, sw1, sb1, slng, slnb, sw2, sb2, sw3, sb3,
                                              synco, desync);
    reduce_kernel<<<1, 1024, 0, stream>>>(phases, order, coh);
}

// Round 2
// 1669.440 us; speedup vs baseline: 1.7533x; 1.7533x over previous
//
#include <hip/hip_runtime.h>
#include <hip/hip_bf16.h>
#include <hip/hip_fp16.h>
#include <math.h>

#define NN 8192
#define DD 256
#define HH 128
#define RPB 16
#define DT_F 0.01f
#define TWO_PI_F 6.28318530717958647692f

typedef _Float16 __h2 __attribute__((ext_vector_type(2)));

__device__ __forceinline__ float fdot2h(__h2 a, __h2 b, float c) {
#if __has_builtin(__builtin_amdgcn_fdot2)
    return __builtin_amdgcn_fdot2(a, b, c, false);
#else
    return c + (float)a[0] * (float)b[0] + (float)a[1] * (float)b[1];
#endif
}

__device__ __forceinline__ float gelu_exact(float t) {
    return 0.5f * t * (1.f + erff(t * 0.70710678118654752440f));
}
__device__ __forceinline__ float sigmoidf(float t) {
    return 1.f / (1.f + expf(-t));
}

// ---------------- A fp32 -> fp16 conversion ---------------------------------
__global__ __launch_bounds__(256) void convert_kernel(
    const float* __restrict__ A, __half* __restrict__ Ah)
{
    size_t i = (size_t)blockIdx.x * 256 + threadIdx.x;
    size_t stride = (size_t)gridDim.x * 256;
    const size_t n8 = (size_t)NN * NN / 8;
    for (size_t j = i; j < n8; j += stride) {
        float4 v0 = ((const float4*)A)[j * 2];
        float4 v1 = ((const float4*)A)[j * 2 + 1];
        union { __half h[8]; float4 f; } u;
        u.h[0] = __float2half_rn(v0.x);
        u.h[1] = __float2half_rn(v0.y);
        u.h[2] = __float2half_rn(v0.z);
        u.h[3] = __float2half_rn(v0.w);
        u.h[4] = __float2half_rn(v1.x);
        u.h[5] = __float2half_rn(v1.y);
        u.h[6] = __float2half_rn(v1.z);
        u.h[7] = __float2half_rn(v1.w);
        ((float4*)Ah)[j] = u.f;
    }
}

// ---------------- pre: frequencies, coupling, phases0, cos/sin snapshot ----
__global__ __launch_bounds__(256) void pre_kernel(
    const float* __restrict__ x,
    const float* __restrict__ fw1, const float* __restrict__ fb1,
    const float* __restrict__ flng, const float* __restrict__ flnb,
    const float* __restrict__ fw2, const float* __restrict__ fb2,
    const float* __restrict__ fw3, const float* __restrict__ fb3,
    const float* __restrict__ cw1, const float* __restrict__ cb1,
    const float* __restrict__ cw2, const float* __restrict__ cb2,
    const float* __restrict__ gcp,
    float* __restrict__ freq_out, float* __restrict__ coup_out,
    float* __restrict__ cs_ws, float* __restrict__ phases_out,
    float* __restrict__ pc0f, float* __restrict__ ps0f,
    __half* __restrict__ pc0h, __half* __restrict__ ps0h)
{
    __shared__ float xs[RPB][DD];
    __shared__ float h1[RPB][DD];
    __shared__ float h2[RPB][HH];
    __shared__ float hc[RPB][HH];
    const int tid = threadIdx.x;
    const int base_row = blockIdx.x * RPB;

    // load x tile
    {
        const float4* xg = (const float4*)(x + (size_t)base_row * DD);
        float4* xv = (float4*)&xs[0][0];
        for (int i = tid; i < RPB * DD / 4; i += 256) xv[i] = xg[i];
    }
    __syncthreads();

    // h1 = x @ fw1 + fb1
    {
        float acc[RPB];
#pragma unroll
        for (int r = 0; r < RPB; ++r) acc[r] = 0.f;
        const int c = tid;
        for (int k = 0; k < DD; k += 4) {
            float w0 = fw1[(k + 0) * DD + c];
            float w1 = fw1[(k + 1) * DD + c];
            float w2 = fw1[(k + 2) * DD + c];
            float w3 = fw1[(k + 3) * DD + c];
#pragma unroll
            for (int r = 0; r < RPB; ++r) {
                float4 xv = *(const float4*)&xs[r][k];
                acc[r] += xv.x * w0 + xv.y * w1 + xv.z * w2 + xv.w * w3;
            }
        }
        float bb = fb1[c];
#pragma unroll
        for (int r = 0; r < RPB; ++r) h1[r][c] = acc[r] + bb;
    }
    __syncthreads();

    // LN + tanh per row (one wave per row)
    {
        const int wave = tid >> 6, lane = tid & 63;
        for (int r = wave; r < RPB; r += 4) {
            float v0 = h1[r][lane], v1 = h1[r][lane + 64], v2 = h1[r][lane + 128], v3 = h1[r][lane + 192];
            float s = v0 + v1 + v2 + v3;
            for (int off = 32; off; off >>= 1) s += __shfl_xor(s, off);
            float m = s * (1.f / DD);
            float d0 = v0 - m, d1 = v1 - m, d2 = v2 - m, d3 = v3 - m;
            float q = d0 * d0 + d1 * d1 + d2 * d2 + d3 * d3;
            for (int off = 32; off; off >>= 1) q += __shfl_xor(q, off);
            float rstd = rsqrtf(q * (1.f / DD) + 1e-5f);
            h1[r][lane]       = tanhf(d0 * rstd * flng[lane]       + flnb[lane]);
            h1[r][lane + 64]  = tanhf(d1 * rstd * flng[lane + 64]  + flnb[lane + 64]);
            h1[r][lane + 128] = tanhf(d2 * rstd * flng[lane + 128] + flnb[lane + 128]);
            h1[r][lane + 192] = tanhf(d3 * rstd * flng[lane + 192] + flnb[lane + 192]);
        }
    }
    __syncthreads();

    // h2 = tanh(h1 @ fw2 + fb2)  [threads 0..127] ; hc = gelu(x @ cw1 + cb1) [threads 128..255]
    if (tid < HH) {
        const int c = tid;
        float acc[RPB];
#pragma unroll
        for (int r = 0; r < RPB; ++r) acc[r] = 0.f;
        for (int k = 0; k < DD; k += 4) {
            float w0 = fw2[(k + 0) * HH + c];
            float w1 = fw2[(k + 1) * HH + c];
            float w2 = fw2[(k + 2) * HH + c];
            float w3 = fw2[(k + 3) * HH + c];
#pragma unroll
            for (int r = 0; r < RPB; ++r) {
                float4 xv = *(const float4*)&h1[r][k];
                acc[r] += xv.x * w0 + xv.y * w1 + xv.z * w2 + xv.w * w3;
            }
        }
        float bb = fb2[c];
#pragma unroll
        for (int r = 0; r < RPB; ++r) h2[r][c] = tanhf(acc[r] + bb);
    } else {
        const int c = tid - HH;
        float acc[RPB];
#pragma unroll
        for (int r = 0; r < RPB; ++r) acc[r] = 0.f;
        for (int k = 0; k < DD; k += 4) {
            float w0 = cw1[(k + 0) * HH + c];
            float w1 = cw1[(k + 1) * HH + c];
            float w2 = cw1[(k + 2) * HH + c];
            float w3 = cw1[(k + 3) * HH + c];
#pragma unroll
            for (int r = 0; r < RPB; ++r) {
                float4 xv = *(const float4*)&xs[r][k];
                acc[r] += xv.x * w0 + xv.y * w1 + xv.z * w2 + xv.w * w3;
            }
        }
        float bb = cb1[c];
#pragma unroll
        for (int r = 0; r < RPB; ++r) {
            float t = acc[r] + bb;
            hc[r][c] = gelu_exact(t);
        }
    }
    __syncthreads();

    // freq / coupling / phases0 : one wave per row
    {
        const int wave = tid >> 6, lane = tid & 63;
        float gc = fminf(fmaxf(gcp[0], 0.1f), 2.0f);
        for (int r = wave; r < RPB; r += 4) {
            float f = h2[r][lane] * fw3[lane] + h2[r][lane + 64] * fw3[lane + 64];
            for (int off = 32; off; off >>= 1) f += __shfl_xor(f, off);
            float cpl = hc[r][lane] * cw2[lane] + hc[r][lane + 64] * cw2[lane + 64];
            for (int off = 32; off; off >>= 1) cpl += __shfl_xor(cpl, off);
            float ssum = 0.f, csum = 0.f;
#pragma unroll
            for (int j = 0; j < 4; ++j) {
                int idx = lane + 64 * j;
                float xv = xs[r][idx];
                float fi = (float)idx;
                ssum += xv * sinf(fi);
                csum += xv * cosf(fi);
            }
            for (int off = 32; off; off >>= 1) {
                ssum += __shfl_xor(ssum, off);
                csum += __shfl_xor(csum, off);
            }
            if (lane == 0) {
                int row = base_row + r;
                freq_out[row] = f + fb3[0];
                float sg = sigmoidf(cpl + cb2[0]);
                coup_out[row] = sg;
                cs_ws[row] = sg * gc;
                float ph = atan2f(ssum, csum);
                phases_out[row] = ph;
                float cph = cosf(ph), sph = sinf(ph);
                pc0f[row] = cph;
                ps0f[row] = sph;
                pc0h[row] = __float2half_rn(cph);
                ps0h[row] = __float2half_rn(sph);
            }
        }
    }
}

// ---------------- one Kuramoto step (fp16 A): fused matvec + phase update ---
#define SROWS 8      // rows per block (4 waves x 2 rows)
__global__ __launch_bounds__(256) void step_kernel_h(
    const __half* __restrict__ A,
    const __half* __restrict__ pc_in, const __half* __restrict__ ps_in,
    const float* __restrict__ freq, const float* __restrict__ cs,
    float* __restrict__ phases,
    __half* __restrict__ pc_out, __half* __restrict__ ps_out)
{
    __shared__ __half pcs[NN];   // 16 KB
    __shared__ __half pss[NN];   // 16 KB
    const int tid = threadIdx.x, lane = tid & 63, wave = tid >> 6;
    for (int i = tid; i < NN / 8; i += 256) {
        ((float4*)pcs)[i] = ((const float4*)pc_in)[i];
        ((float4*)pss)[i] = ((const float4*)ps_in)[i];
    }
    __syncthreads();

    const int row0 = blockIdx.x * SROWS + wave * 2;
    const float4* Ar0 = (const float4*)(A + (size_t)(row0 + 0) * NN);
    const float4* Ar1 = (const float4*)(A + (size_t)(row0 + 1) * NN);
    float lac0 = 0.f, las0 = 0.f, lac1 = 0.f, las1 = 0.f;
#pragma unroll 4
    for (int it = 0; it < NN / 8 / 64; ++it) {   // 16 iters, 8 cols each
        const int idx = it * 64 + lane;
        float4 av0 = Ar0[idx];
        float4 av1 = Ar1[idx];
        float4 cv = ((const float4*)pcs)[idx];
        float4 sv = ((const float4*)pss)[idx];
        const __h2* a0 = (const __h2*)&av0;
        const __h2* a1 = (const __h2*)&av1;
        const __h2* ch = (const __h2*)&cv;
        const __h2* sh = (const __h2*)&sv;
#pragma unroll
        for (int q = 0; q < 4; ++q) {
            lac0 = fdot2h(a0[q], ch[q], lac0);
            las0 = fdot2h(a0[q], sh[q], las0);
            lac1 = fdot2h(a1[q], ch[q], lac1);
            las1 = fdot2h(a1[q], sh[q], las1);
        }
    }
    for (int off = 32; off; off >>= 1) {
        lac0 += __shfl_xor(lac0, off);
        las0 += __shfl_xor(las0, off);
        lac1 += __shfl_xor(lac1, off);
        las1 += __shfl_xor(las1, off);
    }
    if (lane == 0) {
#pragma unroll
        for (int rr = 0; rr < 2; ++rr) {
            const int row = row0 + rr;
            float c = rr ? lac1 : lac0;
            float s = rr ? las1 : las0;
            float ph = phases[row];
            float ce = atan2f(s, c + 1e-8f) - ph;
            float dphi = freq[row] + cs[row] * sinf(ce);
            float pn = ph + DT_F * dphi;
            pn = fmodf(pn, TWO_PI_F);
            if (pn < 0.f) pn += TWO_PI_F;
            phases[row] = pn;
            pc_out[row] = __float2half_rn(cosf(pn));
            ps_out[row] = __float2half_rn(sinf(pn));
        }
    }
}

// ---------------- fp32 fallback step (if ws too small for A_half) ----------
#define CHUNK 4096
__global__ __launch_bounds__(256) void step_kernel(
    const float* __restrict__ A,
    const float* __restrict__ pc_in, const float* __restrict__ ps_in,
    const float* __restrict__ freq, const float* __restrict__ cs,
    float* __restrict__ phases,
    float* __restrict__ pc_out, float* __restrict__ ps_out)
{
    __shared__ float pcs[CHUNK];
    __shared__ float pss[CHUNK];
    const int tid = threadIdx.x, lane = tid & 63, wave = tid >> 6;
    const int row0 = blockIdx.x * SROWS + wave * (SROWS / 4);
    float accC[SROWS / 4], accS[SROWS / 4];
#pragma unroll
    for (int rr = 0; rr < SROWS / 4; ++rr) { accC[rr] = 0.f; accS[rr] = 0.f; }

    for (int ch = 0; ch < NN / CHUNK; ++ch) {
        const float4* pcg = (const float4*)(pc_in + ch * CHUNK);
        const float4* psg = (const float4*)(ps_in + ch * CHUNK);
        for (int i = tid; i < CHUNK / 4; i += 256) {
            ((float4*)pcs)[i] = pcg[i];
            ((float4*)pss)[i] = psg[i];
        }
        __syncthreads();
#pragma unroll
        for (int rr = 0; rr < SROWS / 4; ++rr) {
            const float4* Ar = (const float4*)(A + (size_t)(row0 + rr) * NN + ch * CHUNK);
            float lac = 0.f, las = 0.f;
#pragma unroll 4
            for (int it = 0; it < CHUNK / 256; ++it) {
                int c4 = it * 64 + lane;
                float4 a = Ar[c4];
                float4 c = ((const float4*)pcs)[c4];
                float4 s = ((const float4*)pss)[c4];
                lac += a.x * c.x + a.y * c.y + a.z * c.z + a.w * c.w;
                las += a.x * s.x + a.y * s.y + a.z * s.z + a.w * s.w;
            }
            accC[rr] += lac;
            accS[rr] += las;
        }
        __syncthreads();
    }

#pragma unroll
    for (int rr = 0; rr < SROWS / 4; ++rr) {
        float c = accC[rr], s = accS[rr];
        for (int off = 32; off; off >>= 1) {
            c += __shfl_xor(c, off);
            s += __shfl_xor(s, off);
        }
        if (lane == 0) {
            int row = row0 + rr;
            float ph = phases[row];
            float ce = atan2f(s, c + 1e-8f) - ph;
            float dphi = freq[row] + cs[row] * sinf(ce);
            float pn = ph + DT_F * dphi;
            pn = fmodf(pn, TWO_PI_F);
            if (pn < 0.f) pn += TWO_PI_F;
            phases[row] = pn;
            pc_out[row] = cosf(pn);
            ps_out[row] = sinf(pn);
        }
    }
}

// ---------------- post: sync_input, sync MLP -> desync ----------------------
#define SD 260
#define SDP 264
__global__ __launch_bounds__(256) void post_kernel(
    const float* __restrict__ x, const float* __restrict__ phases,
    const float* __restrict__ sw1, const float* __restrict__ sb1,
    const float* __restrict__ slng, const float* __restrict__ slnb,
    const float* __restrict__ sw2, const float* __restrict__ sb2,
    const float* __restrict__ sw3, const float* __restrict__ sb3,
    float* __restrict__ sync_out, float* __restrict__ desync_out)
{
    __shared__ float xs[RPB][SDP];
    __shared__ float h1[RPB][DD];
    __shared__ float h2[RPB][HH];
    const int tid = threadIdx.x;
    const int base_row = blockIdx.x * RPB;

    // load x tile
    for (int i = tid; i < RPB * DD / 4; i += 256) {
        int r = i / (DD / 4), c4 = i % (DD / 4);
        *(float4*)&xs[r][c4 * 4] = ((const float4*)(x + (size_t)(base_row + r) * DD))[c4];
    }
    if (tid < RPB) {
        float p = phases[base_row + tid];
        xs[tid][256] = cosf(p);
        xs[tid][257] = sinf(p);
        xs[tid][258] = cosf(2.f * p);
        xs[tid][259] = sinf(2.f * p);
    }
    __syncthreads();

    // write sync_input
    for (int i = tid; i < RPB * SD; i += 256) {
        int r = i / SD, c = i % SD;
        sync_out[(size_t)(base_row + r) * SD + c] = xs[r][c];
    }

    // h1 = sync_input @ sw1 + sb1
    {
        float acc[RPB];
#pragma unroll
        for (int r = 0; r < RPB; ++r) acc[r] = 0.f;
        const int c = tid;
        for (int k = 0; k < SD; k += 4) {
            float w0 = sw1[(k + 0) * DD + c];
            float w1 = sw1[(k + 1) * DD + c];
            float w2 = sw1[(k + 2) * DD + c];
            float w3 = sw1[(k + 3) * DD + c];
#pragma unroll
            for (int r = 0; r < RPB; ++r) {
                float4 xv = *(const float4*)&xs[r][k];
                acc[r] += xv.x * w0 + xv.y * w1 + xv.z * w2 + xv.w * w3;
            }
        }
        float bb = sb1[c];
#pragma unroll
        for (int r = 0; r < RPB; ++r) h1[r][c] = acc[r] + bb;
    }
    __syncthreads();

    // LN + GELU per row
    {
        const int wave = tid >> 6, lane = tid & 63;
        for (int r = wave; r < RPB; r += 4) {
            float v0 = h1[r][lane], v1 = h1[r][lane + 64], v2 = h1[r][lane + 128], v3 = h1[r][lane + 192];
            float s = v0 + v1 + v2 + v3;
            for (int off = 32; off; off >>= 1) s += __shfl_xor(s, off);
            float m = s * (1.f / DD);
            float d0 = v0 - m, d1 = v1 - m, d2 = v2 - m, d3 = v3 - m;
            float q = d0 * d0 + d1 * d1 + d2 * d2 + d3 * d3;
            for (int off = 32; off; off >>= 1) q += __shfl_xor(q, off);
            float rstd = rsqrtf(q * (1.f / DD) + 1e-5f);
            h1[r][lane]       = gelu_exact(d0 * rstd * slng[lane]       + slnb[lane]);
            h1[r][lane + 64]  = gelu_exact(d1 * rstd * slng[lane + 64]  + slnb[lane + 64]);
            h1[r][lane + 128] = gelu_exact(d2 * rstd * slng[lane + 128] + slnb[lane + 128]);
            h1[r][lane + 192] = gelu_exact(d3 * rstd * slng[lane + 192] + slnb[lane + 192]);
        }
    }
    __syncthreads();

    // h2 = gelu(h1 @ sw2 + sb2)  [threads 0..127]
    if (tid < HH) {
        const int c = tid;
        float acc[RPB];
#pragma unroll
        for (int r = 0; r < RPB; ++r) acc[r] = 0.f;
        for (int k = 0; k < DD; k += 4) {
            float w0 = sw2[(k + 0) * HH + c];
            float w1 = sw2[(k + 1) * HH + c];
            float w2 = sw2[(k + 2) * HH + c];
            float w3 = sw2[(k + 3) * HH + c];
#pragma unroll
            for (int r = 0; r < RPB; ++r) {
                float4 xv = *(const float4*)&h1[r][k];
                acc[r] += xv.x * w0 + xv.y * w1 + xv.z * w2 + xv.w * w3;
            }
        }
        float bb = sb2[c];
#pragma unroll
        for (int r = 0; r < RPB; ++r) h2[r][c] = gelu_exact(acc[r] + bb);
    }
    __syncthreads();

    // desync = sigmoid(h2 @ sw3 + sb3) : one wave per row
    {
        const int wave = tid >> 6, lane = tid & 63;
        for (int r = wave; r < RPB; r += 4) {
            float t = h2[r][lane] * sw3[lane] + h2[r][lane + 64] * sw3[lane + 64];
            for (int off = 32; off; off >>= 1) t += __shfl_xor(t, off);
            if (lane == 0) desync_out[base_row + r] = sigmoidf(t + sb3[0]);
        }
    }
}

// ---------------- global scalar reductions ---------------------------------
__global__ __launch_bounds__(1024) void reduce_kernel(
    const float* __restrict__ phases,
    float* __restrict__ order_out, float* __restrict__ coh_out)
{
    __shared__ double red[16][4];
    const int tid = threadIdx.x;
    double sc = 0, ss = 0, sp = 0, spp = 0;
    for (int i = tid; i < NN; i += 1024) {
        float p = phases[i];
        sc += (double)cosf(p);
        ss += (double)sinf(p);
        sp += (double)p;
        spp += (double)p * (double)p;
    }
    const int lane = tid & 63, wave = tid >> 6;
    for (int off = 32; off; off >>= 1) {
        sc += __shfl_xor(sc, off);
        ss += __shfl_xor(ss, off);
        sp += __shfl_xor(sp, off);
        spp += __shfl_xor(spp, off);
    }
    if (lane == 0) { red[wave][0] = sc; red[wave][1] = ss; red[wave][2] = sp; red[wave][3] = spp; }
    __syncthreads();
    if (tid == 0) {
        sc = 0; ss = 0; sp = 0; spp = 0;
        for (int w = 0; w < 16; ++w) { sc += red[w][0]; ss += red[w][1]; sp += red[w][2]; spp += red[w][3]; }
        double mc = sc / NN, ms = ss / NN;
        order_out[0] = (float)sqrt(mc * mc + ms * ms);
        double var = (spp - sp * sp / NN) / (NN - 1);
        if (var < 0) var = 0;
        coh_out[0] = (float)(1.0 / (1.0 + sqrt(var)));
    }
}

extern "C" void kernel_launch(void* const* d_in, const int* in_sizes, int n_in,
                              void* d_out, int out_size, void* d_ws, size_t ws_size,
                              hipStream_t stream) {
    const float* x    = (const float*)d_in[0];
    const float* A    = (const float*)d_in[1];
    const float* fw1  = (const float*)d_in[2];
    const float* fb1  = (const float*)d_in[3];
    const float* flng = (const float*)d_in[4];
    const float* flnb = (const float*)d_in[5];
    const float* fw2  = (const float*)d_in[6];
    const float* fb2  = (const float*)d_in[7];
    const float* fw3  = (const float*)d_in[8];
    const float* fb3  = (const float*)d_in[9];
    const float* cw1  = (const float*)d_in[10];
    const float* cb1  = (const float*)d_in[11];
    const float* cw2  = (const float*)d_in[12];
    const float* cb2  = (const float*)d_in[13];
    const float* sw1  = (const float*)d_in[14];
    const float* sb1  = (const float*)d_in[15];
    const float* slng = (const float*)d_in[16];
    const float* slnb = (const float*)d_in[17];
    const float* sw2  = (const float*)d_in[18];
    const float* sb2  = (const float*)d_in[19];
    const float* sw3  = (const float*)d_in[20];
    const float* sb3  = (const float*)d_in[21];
    const float* gcp  = (const float*)d_in[22];

    float* out    = (float*)d_out;
    float* desync = out;                    // 8192
    float* order  = out + 8192;             // 1
    float* phases = out + 8193;             // 8192
    float* freqo  = out + 16385;            // 8192
    float* coupo  = out + 24577;            // 8192
    float* synco  = out + 32769;            // 8192*260
    float* coh    = out + 2162689;          // 1

    char* wsb = (char*)d_ws;
    float*  cs   = (float*)(wsb + 0);        // 32 KB
    float*  pcAf = (float*)(wsb + 32768);    // 32 KB
    float*  psAf = (float*)(wsb + 65536);
    float*  pcBf = (float*)(wsb + 98304);
    float*  psBf = (float*)(wsb + 131072);
    __half* pcAh = (__half*)(wsb + 163840);  // 16 KB
    __half* psAh = (__half*)(wsb + 180224);
    __half* pcBh = (__half*)(wsb + 196608);
    __half* psBh = (__half*)(wsb + 212992);
    __half* Ah   = (__half*)(wsb + 262144);  // 128 MiB

    const bool use16 = ws_size >= (size_t)262144 + (size_t)NN * NN * 2;

    if (use16) {
        convert_kernel<<<8192, 256, 0, stream>>>(A, Ah);
    }
    pre_kernel<<<NN / RPB, 256, 0, stream>>>(x, fw1, fb1, flng, flnb, fw2, fb2, fw3, fb3,
                                             cw1, cb1, cw2, cb2, gcp,
                                             freqo, coupo, cs, phases,
                                             pcAf, psAf, pcAh, psAh);
    if (use16) {
        for (int t = 0; t < 60; ++t) {
            const __half* pin  = (t & 1) ? pcBh : pcAh;
            const __half* sin_ = (t & 1) ? psBh : psAh;
            __half* pout = (t & 1) ? pcAh : pcBh;
            __half* sout = (t & 1) ? psAh : psBh;
            step_kernel_h<<<NN / SROWS, 256, 0, stream>>>(Ah, pin, sin_, freqo, cs, phases, pout, sout);
        }
    } else {
        for (int t = 0; t < 60; ++t) {
            const float* pin  = (t & 1) ? pcBf : pcAf;
            const float* sin_ = (t & 1) ? psBf : psAf;
            float* pout = (t & 1) ? pcAf : pcBf;
            float* sout = (t & 1) ? psAf : psBf;
            step_kernel<<<NN / SROWS, 256, 0, stream>>>(A, pin, sin_, freqo, cs, phases, pout, sout);
        }
    }
    post_kernel<<<NN / RPB, 256, 0, stream>>>(x, phases, sw1, sb1, slng, slnb, sw2, sb2, sw3, sb3,
                                              synco, desync);
    reduce_kernel<<<1, 1024, 0, stream>>>(phases, order, coh);
}

// Round 3
// 1486.398 us; speedup vs baseline: 1.9693x; 1.1231x over previous
//
#include <hip/hip_runtime.h>
#include <hip/hip_bf16.h>
#include <hip/hip_fp16.h>
#include <math.h>

#define NN 8192
#define DD 256
#define HH 128
#define RPB 16
#define DT_F 0.01f
#define TWO_PI_F 6.28318530717958647692f
#define ROWB 12288   // packed bytes per row: 8192 low-byte + 4096 high-nibble

__device__ __forceinline__ float gelu_exact(float t) {
    return 0.5f * t * (1.f + erff(t * 0.70710678118654752440f));
}
__device__ __forceinline__ float sigmoidf(float t) {
    return 1.f / (1.f + expf(-t));
}

// ---------------- A fp32 -> packed 12-bit conversion ------------------------
// Per row: bytes [0,8192) = low 8 bits of q, bytes [8192,12288) = high nibbles
// q = round(a * 4095), a in [0,1].
__global__ __launch_bounds__(256) void convert_pack_kernel(
    const float* __restrict__ A, unsigned char* __restrict__ Ap)
{
    const int row = blockIdx.x >> 2;
    const int seg = blockIdx.x & 3;
    const int t = threadIdx.x;
    const int col0 = seg * 2048 + t * 8;
    const float* src = A + (size_t)row * NN + col0;
    float4 f0 = ((const float4*)src)[0];
    float4 f1 = ((const float4*)src)[1];
    float v[8] = {f0.x, f0.y, f0.z, f0.w, f1.x, f1.y, f1.z, f1.w};
    unsigned int q[8];
#pragma unroll
    for (int k = 0; k < 8; ++k) {
        float c = fminf(fmaxf(v[k], 0.f), 1.f);
        q[k] = (unsigned int)__float2int_rn(c * 4095.f);
    }
    unsigned int lo0 = (q[0] & 0xFF) | ((q[1] & 0xFF) << 8) | ((q[2] & 0xFF) << 16) | ((q[3] & 0xFF) << 24);
    unsigned int lo1 = (q[4] & 0xFF) | ((q[5] & 0xFF) << 8) | ((q[6] & 0xFF) << 16) | ((q[7] & 0xFF) << 24);
    unsigned int nib = (q[0] >> 8) | ((q[1] >> 8) << 4) | ((q[2] >> 8) << 8) | ((q[3] >> 8) << 12)
                     | ((q[4] >> 8) << 16) | ((q[5] >> 8) << 20) | ((q[6] >> 8) << 24) | ((q[7] >> 8) << 28);
    unsigned char* rowp = Ap + (size_t)row * ROWB;
    ((uint2*)rowp)[seg * 256 + t] = make_uint2(lo0, lo1);
    ((unsigned int*)(rowp + 8192))[seg * 256 + t] = nib;
}

// ---------------- pre: frequencies, coupling, phases0, cos/sin snapshot ----
__global__ __launch_bounds__(256) void pre_kernel(
    const float* __restrict__ x,
    const float* __restrict__ fw1, const float* __restrict__ fb1,
    const float* __restrict__ flng, const float* __restrict__ flnb,
    const float* __restrict__ fw2, const float* __restrict__ fb2,
    const float* __restrict__ fw3, const float* __restrict__ fb3,
    const float* __restrict__ cw1, const float* __restrict__ cb1,
    const float* __restrict__ cw2, const float* __restrict__ cb2,
    const float* __restrict__ gcp,
    float* __restrict__ freq_out, float* __restrict__ coup_out,
    float* __restrict__ cs_ws, float* __restrict__ phases_out,
    float* __restrict__ pc0f, float* __restrict__ ps0f,
    __half* __restrict__ pc0h, __half* __restrict__ ps0h)
{
    __shared__ float xs[RPB][DD];
    __shared__ float h1[RPB][DD];
    __shared__ float h2[RPB][HH];
    __shared__ float hc[RPB][HH];
    const int tid = threadIdx.x;
    const int base_row = blockIdx.x * RPB;

    // load x tile
    {
        const float4* xg = (const float4*)(x + (size_t)base_row * DD);
        float4* xv = (float4*)&xs[0][0];
        for (int i = tid; i < RPB * DD / 4; i += 256) xv[i] = xg[i];
    }
    __syncthreads();

    // h1 = x @ fw1 + fb1
    {
        float acc[RPB];
#pragma unroll
        for (int r = 0; r < RPB; ++r) acc[r] = 0.f;
        const int c = tid;
        for (int k = 0; k < DD; k += 4) {
            float w0 = fw1[(k + 0) * DD + c];
            float w1 = fw1[(k + 1) * DD + c];
            float w2 = fw1[(k + 2) * DD + c];
            float w3 = fw1[(k + 3) * DD + c];
#pragma unroll
            for (int r = 0; r < RPB; ++r) {
                float4 xv = *(const float4*)&xs[r][k];
                acc[r] += xv.x * w0 + xv.y * w1 + xv.z * w2 + xv.w * w3;
            }
        }
        float bb = fb1[c];
#pragma unroll
        for (int r = 0; r < RPB; ++r) h1[r][c] = acc[r] + bb;
    }
    __syncthreads();

    // LN + tanh per row (one wave per row)
    {
        const int wave = tid >> 6, lane = tid & 63;
        for (int r = wave; r < RPB; r += 4) {
            float v0 = h1[r][lane], v1 = h1[r][lane + 64], v2 = h1[r][lane + 128], v3 = h1[r][lane + 192];
            float s = v0 + v1 + v2 + v3;
            for (int off = 32; off; off >>= 1) s += __shfl_xor(s, off);
            float m = s * (1.f / DD);
            float d0 = v0 - m, d1 = v1 - m, d2 = v2 - m, d3 = v3 - m;
            float q = d0 * d0 + d1 * d1 + d2 * d2 + d3 * d3;
            for (int off = 32; off; off >>= 1) q += __shfl_xor(q, off);
            float rstd = rsqrtf(q * (1.f / DD) + 1e-5f);
            h1[r][lane]       = tanhf(d0 * rstd * flng[lane]       + flnb[lane]);
            h1[r][lane + 64]  = tanhf(d1 * rstd * flng[lane + 64]  + flnb[lane + 64]);
            h1[r][lane + 128] = tanhf(d2 * rstd * flng[lane + 128] + flnb[lane + 128]);
            h1[r][lane + 192] = tanhf(d3 * rstd * flng[lane + 192] + flnb[lane + 192]);
        }
    }
    __syncthreads();

    // h2 = tanh(h1 @ fw2 + fb2)  [threads 0..127] ; hc = gelu(x @ cw1 + cb1) [threads 128..255]
    if (tid < HH) {
        const int c = tid;
        float acc[RPB];
#pragma unroll
        for (int r = 0; r < RPB; ++r) acc[r] = 0.f;
        for (int k = 0; k < DD; k += 4) {
            float w0 = fw2[(k + 0) * HH + c];
            float w1 = fw2[(k + 1) * HH + c];
            float w2 = fw2[(k + 2) * HH + c];
            float w3 = fw2[(k + 3) * HH + c];
#pragma unroll
            for (int r = 0; r < RPB; ++r) {
                float4 xv = *(const float4*)&h1[r][k];
                acc[r] += xv.x * w0 + xv.y * w1 + xv.z * w2 + xv.w * w3;
            }
        }
        float bb = fb2[c];
#pragma unroll
        for (int r = 0; r < RPB; ++r) h2[r][c] = tanhf(acc[r] + bb);
    } else {
        const int c = tid - HH;
        float acc[RPB];
#pragma unroll
        for (int r = 0; r < RPB; ++r) acc[r] = 0.f;
        for (int k = 0; k < DD; k += 4) {
            float w0 = cw1[(k + 0) * HH + c];
            float w1 = cw1[(k + 1) * HH + c];
            float w2 = cw1[(k + 2) * HH + c];
            float w3 = cw1[(k + 3) * HH + c];
#pragma unroll
            for (int r = 0; r < RPB; ++r) {
                float4 xv = *(const float4*)&xs[r][k];
                acc[r] += xv.x * w0 + xv.y * w1 + xv.z * w2 + xv.w * w3;
            }
        }
        float bb = cb1[c];
#pragma unroll
        for (int r = 0; r < RPB; ++r) {
            float t = acc[r] + bb;
            hc[r][c] = gelu_exact(t);
        }
    }
    __syncthreads();

    // freq / coupling / phases0 : one wave per row
    {
        const int wave = tid >> 6, lane = tid & 63;
        float gc = fminf(fmaxf(gcp[0], 0.1f), 2.0f);
        for (int r = wave; r < RPB; r += 4) {
            float f = h2[r][lane] * fw3[lane] + h2[r][lane + 64] * fw3[lane + 64];
            for (int off = 32; off; off >>= 1) f += __shfl_xor(f, off);
            float cpl = hc[r][lane] * cw2[lane] + hc[r][lane + 64] * cw2[lane + 64];
            for (int off = 32; off; off >>= 1) cpl += __shfl_xor(cpl, off);
            float ssum = 0.f, csum = 0.f;
#pragma unroll
            for (int j = 0; j < 4; ++j) {
                int idx = lane + 64 * j;
                float xv = xs[r][idx];
                float fi = (float)idx;
                ssum += xv * sinf(fi);
                csum += xv * cosf(fi);
            }
            for (int off = 32; off; off >>= 1) {
                ssum += __shfl_xor(ssum, off);
                csum += __shfl_xor(csum, off);
            }
            if (lane == 0) {
                int row = base_row + r;
                freq_out[row] = f + fb3[0];
                float sg = sigmoidf(cpl + cb2[0]);
                coup_out[row] = sg;
                cs_ws[row] = sg * gc;
                float ph = atan2f(ssum, csum);
                phases_out[row] = ph;
                float cph = cosf(ph), sph = sinf(ph);
                pc0f[row] = cph;
                ps0f[row] = sph;
                pc0h[row] = __float2half_rn(cph);
                ps0h[row] = __float2half_rn(sph);
            }
        }
    }
}

// ---------------- one Kuramoto step (12-bit packed A) -----------------------
#define SROWS 8      // rows per block (4 waves x 2 rows)
__global__ __launch_bounds__(256) void step_kernel_p(
    const unsigned char* __restrict__ Ap,
    const __half* __restrict__ pc_in, const __half* __restrict__ ps_in,
    const float* __restrict__ freq, const float* __restrict__ cs,
    float* __restrict__ phases,
    __half* __restrict__ pc_out, __half* __restrict__ ps_out)
{
    __shared__ __half pcs[NN];   // 16 KB
    __shared__ __half pss[NN];   // 16 KB
    const int tid = threadIdx.x, lane = tid & 63, wave = tid >> 6;
    for (int i = tid; i < NN / 8; i += 256) {
        ((float4*)pcs)[i] = ((const float4*)pc_in)[i];
        ((float4*)pss)[i] = ((const float4*)ps_in)[i];
    }
    __syncthreads();

    const int row0 = blockIdx.x * SROWS + wave * 2;
    const unsigned char* r0p = Ap + (size_t)(row0 + 0) * ROWB;
    const unsigned char* r1p = Ap + (size_t)(row0 + 1) * ROWB;
    const uint2* lo0p = (const uint2*)r0p;
    const uint2* lo1p = (const uint2*)r1p;
    const unsigned int* nb0p = (const unsigned int*)(r0p + 8192);
    const unsigned int* nb1p = (const unsigned int*)(r1p + 8192);

    float lac0 = 0.f, las0 = 0.f, lac1 = 0.f, las1 = 0.f;
#pragma unroll 4
    for (int it = 0; it < NN / 8 / 64; ++it) {   // 16 iters, 8 cols each
        const int idx = it * 64 + lane;
        uint2 lo0 = lo0p[idx];
        uint2 lo1 = lo1p[idx];
        unsigned int nb0 = nb0p[idx];
        unsigned int nb1 = nb1p[idx];
        float4 cv = ((const float4*)pcs)[idx];
        float4 sv = ((const float4*)pss)[idx];
        const __half* ch = (const __half*)&cv;
        const __half* sh = (const __half*)&sv;
#pragma unroll
        for (int k = 0; k < 4; ++k) {
            float cf = __half2float(ch[k]);
            float sf = __half2float(sh[k]);
            float q0 = (float)(((lo0.x >> (8 * k)) & 0xFFu) | (((nb0 >> (4 * k)) & 0xFu) << 8));
            float q1 = (float)(((lo1.x >> (8 * k)) & 0xFFu) | (((nb1 >> (4 * k)) & 0xFu) << 8));
            lac0 = fmaf(q0, cf, lac0);
            las0 = fmaf(q0, sf, las0);
            lac1 = fmaf(q1, cf, lac1);
            las1 = fmaf(q1, sf, las1);
        }
#pragma unroll
        for (int k = 0; k < 4; ++k) {
            float cf = __half2float(ch[4 + k]);
            float sf = __half2float(sh[4 + k]);
            float q0 = (float)(((lo0.y >> (8 * k)) & 0xFFu) | (((nb0 >> (16 + 4 * k)) & 0xFu) << 8));
            float q1 = (float)(((lo1.y >> (8 * k)) & 0xFFu) | (((nb1 >> (16 + 4 * k)) & 0xFu) << 8));
            lac0 = fmaf(q0, cf, lac0);
            las0 = fmaf(q0, sf, las0);
            lac1 = fmaf(q1, cf, lac1);
            las1 = fmaf(q1, sf, las1);
        }
    }
    for (int off = 32; off; off >>= 1) {
        lac0 += __shfl_xor(lac0, off);
        las0 += __shfl_xor(las0, off);
        lac1 += __shfl_xor(lac1, off);
        las1 += __shfl_xor(las1, off);
    }
    if (lane == 0) {
        const float inv = 1.f / 4095.f;
#pragma unroll
        for (int rr = 0; rr < 2; ++rr) {
            const int row = row0 + rr;
            float c = (rr ? lac1 : lac0) * inv;
            float s = (rr ? las1 : las0) * inv;
            float ph = phases[row];
            float ce = atan2f(s, c + 1e-8f) - ph;
            float dphi = freq[row] + cs[row] * sinf(ce);
            float pn = ph + DT_F * dphi;
            pn = fmodf(pn, TWO_PI_F);
            if (pn < 0.f) pn += TWO_PI_F;
            phases[row] = pn;
            pc_out[row] = __float2half_rn(cosf(pn));
            ps_out[row] = __float2half_rn(sinf(pn));
        }
    }
}

// ---------------- fp32 fallback step (if ws too small for packed A) --------
#define CHUNK 4096
__global__ __launch_bounds__(256) void step_kernel(
    const float* __restrict__ A,
    const float* __restrict__ pc_in, const float* __restrict__ ps_in,
    const float* __restrict__ freq, const float* __restrict__ cs,
    float* __restrict__ phases,
    float* __restrict__ pc_out, float* __restrict__ ps_out)
{
    __shared__ float pcs[CHUNK];
    __shared__ float pss[CHUNK];
    const int tid = threadIdx.x, lane = tid & 63, wave = tid >> 6;
    const int row0 = blockIdx.x * SROWS + wave * (SROWS / 4);
    float accC[SROWS / 4], accS[SROWS / 4];
#pragma unroll
    for (int rr = 0; rr < SROWS / 4; ++rr) { accC[rr] = 0.f; accS[rr] = 0.f; }

    for (int ch = 0; ch < NN / CHUNK; ++ch) {
        const float4* pcg = (const float4*)(pc_in + ch * CHUNK);
        const float4* psg = (const float4*)(ps_in + ch * CHUNK);
        for (int i = tid; i < CHUNK / 4; i += 256) {
            ((float4*)pcs)[i] = pcg[i];
            ((float4*)pss)[i] = psg[i];
        }
        __syncthreads();
#pragma unroll
        for (int rr = 0; rr < SROWS / 4; ++rr) {
            const float4* Ar = (const float4*)(A + (size_t)(row0 + rr) * NN + ch * CHUNK);
            float lac = 0.f, las = 0.f;
#pragma unroll 4
            for (int it = 0; it < CHUNK / 256; ++it) {
                int c4 = it * 64 + lane;
                float4 a = Ar[c4];
                float4 c = ((const float4*)pcs)[c4];
                float4 s = ((const float4*)pss)[c4];
                lac += a.x * c.x + a.y * c.y + a.z * c.z + a.w * c.w;
                las += a.x * s.x + a.y * s.y + a.z * s.z + a.w * s.w;
            }
            accC[rr] += lac;
            accS[rr] += las;
        }
        __syncthreads();
    }

#pragma unroll
    for (int rr = 0; rr < SROWS / 4; ++rr) {
        float c = accC[rr], s = accS[rr];
        for (int off = 32; off; off >>= 1) {
            c += __shfl_xor(c, off);
            s += __shfl_xor(s, off);
        }
        if (lane == 0) {
            int row = row0 + rr;
            float ph = phases[row];
            float ce = atan2f(s, c + 1e-8f) - ph;
            float dphi = freq[row] + cs[row] * sinf(ce);
            float pn = ph + DT_F * dphi;
            pn = fmodf(pn, TWO_PI_F);
            if (pn < 0.f) pn += TWO_PI_F;
            phases[row] = pn;
            pc_out[row] = cosf(pn);
            ps_out[row] = sinf(pn);
        }
    }
}

// ---------------- post: sync_input, sync MLP -> desync ----------------------
#define SD 260
#define SDP 264
__global__ __launch_bounds__(256) void post_kernel(
    const float* __restrict__ x, const float* __restrict__ phases,
    const float* __restrict__ sw1, const float* __restrict__ sb1,
    const float* __restrict__ slng, const float* __restrict__ slnb,
    const float* __restrict__ sw2, const float* __restrict__ sb2,
    const float* __restrict__ sw3, const float* __restrict__ sb3,
    float* __restrict__ sync_out, float* __restrict__ desync_out)
{
    __shared__ float xs[RPB][SDP];
    __shared__ float h1[RPB][DD];
    __shared__ float h2[RPB][HH];
    const int tid = threadIdx.x;
    const int base_row = blockIdx.x * RPB;

    // load x tile
    for (int i = tid; i < RPB * DD / 4; i += 256) {
        int r = i / (DD / 4), c4 = i % (DD / 4);
        *(float4*)&xs[r][c4 * 4] = ((const float4*)(x + (size_t)(base_row + r) * DD))[c4];
    }
    if (tid < RPB) {
        float p = phases[base_row + tid];
        xs[tid][256] = cosf(p);
        xs[tid][257] = sinf(p);
        xs[tid][258] = cosf(2.f * p);
        xs[tid][259] = sinf(2.f * p);
    }
    __syncthreads();

    // write sync_input
    for (int i = tid; i < RPB * SD; i += 256) {
        int r = i / SD, c = i % SD;
        sync_out[(size_t)(base_row + r) * SD + c] = xs[r][c];
    }

    // h1 = sync_input @ sw1 + sb1
    {
        float acc[RPB];
#pragma unroll
        for (int r = 0; r < RPB; ++r) acc[r] = 0.f;
        const int c = tid;
        for (int k = 0; k < SD; k += 4) {
            float w0 = sw1[(k + 0) * DD + c];
            float w1 = sw1[(k + 1) * DD + c];
            float w2 = sw1[(k + 2) * DD + c];
            float w3 = sw1[(k + 3) * DD + c];
#pragma unroll
            for (int r = 0; r < RPB; ++r) {
                float4 xv = *(const float4*)&xs[r][k];
                acc[r] += xv.x * w0 + xv.y * w1 + xv.z * w2 + xv.w * w3;
            }
        }
        float bb = sb1[c];
#pragma unroll
        for (int r = 0; r < RPB; ++r) h1[r][c] = acc[r] + bb;
    }
    __syncthreads();

    // LN + GELU per row
    {
        const int wave = tid >> 6, lane = tid & 63;
        for (int r = wave; r < RPB; r += 4) {
            float v0 = h1[r][lane], v1 = h1[r][lane + 64], v2 = h1[r][lane + 128], v3 = h1[r][lane + 192];
            float s = v0 + v1 + v2 + v3;
            for (int off = 32; off; off >>= 1) s += __shfl_xor(s, off);
            float m = s * (1.f / DD);
            float d0 = v0 - m, d1 = v1 - m, d2 = v2 - m, d3 = v3 - m;
            float q = d0 * d0 + d1 * d1 + d2 * d2 + d3 * d3;
            for (int off = 32; off; off >>= 1) q += __shfl_xor(q, off);
            float rstd = rsqrtf(q * (1.f / DD) + 1e-5f);
            h1[r][lane]       = gelu_exact(d0 * rstd * slng[lane]       + slnb[lane]);
            h1[r][lane + 64]  = gelu_exact(d1 * rstd * slng[lane + 64]  + slnb[lane + 64]);
            h1[r][lane + 128] = gelu_exact(d2 * rstd * slng[lane + 128] + slnb[lane + 128]);
            h1[r][lane + 192] = gelu_exact(d3 * rstd * slng[lane + 192] + slnb[lane + 192]);
        }
    }
    __syncthreads();

    // h2 = gelu(h1 @ sw2 + sb2)  [threads 0..127]
    if (tid < HH) {
        const int c = tid;
        float acc[RPB];
#pragma unroll
        for (int r = 0; r < RPB; ++r) acc[r] = 0.f;
        for (int k = 0; k < DD; k += 4) {
            float w0 = sw2[(k + 0) * HH + c];
            float w1 = sw2[(k + 1) * HH + c];
            float w2 = sw2[(k + 2) * HH + c];
            float w3 = sw2[(k + 3) * HH + c];
#pragma unroll
            for (int r = 0; r < RPB; ++r) {
                float4 xv = *(const float4*)&h1[r][k];
                acc[r] += xv.x * w0 + xv.y * w1 + xv.z * w2 + xv.w * w3;
            }
        }
        float bb = sb2[c];
#pragma unroll
        for (int r = 0; r < RPB; ++r) h2[r][c] = gelu_exact(acc[r] + bb);
    }
    __syncthreads();

    // desync = sigmoid(h2 @ sw3 + sb3) : one wave per row
    {
        const int wave = tid >> 6, lane = tid & 63;
        for (int r = wave; r < RPB; r += 4) {
            float t = h2[r][lane] * sw3[lane] + h2[r][lane + 64] * sw3[lane + 64];
            for (int off = 32; off; off >>= 1) t += __shfl_xor(t, off);
            if (lane == 0) desync_out[base_row + r] = sigmoidf(t + sb3[0]);
        }
    }
}

// ---------------- global scalar reductions ---------------------------------
__global__ __launch_bounds__(1024) void reduce_kernel(
    const float* __restrict__ phases,
    float* __restrict__ order_out, float* __restrict__ coh_out)
{
    __shared__ double red[16][4];
    const int tid = threadIdx.x;
    double sc = 0, ss = 0, sp = 0, spp = 0;
    for (int i = tid; i < NN; i += 1024) {
        float p = phases[i];
        sc += (double)cosf(p);
        ss += (double)sinf(p);
        sp += (double)p;
        spp += (double)p * (double)p;
    }
    const int lane = tid & 63, wave = tid >> 6;
    for (int off = 32; off; off >>= 1) {
        sc += __shfl_xor(sc, off);
        ss += __shfl_xor(ss, off);
        sp += __shfl_xor(sp, off);
        spp += __shfl_xor(spp, off);
    }
    if (lane == 0) { red[wave][0] = sc; red[wave][1] = ss; red[wave][2] = sp; red[wave][3] = spp; }
    __syncthreads();
    if (tid == 0) {
        sc = 0; ss = 0; sp = 0; spp = 0;
        for (int w = 0; w < 16; ++w) { sc += red[w][0]; ss += red[w][1]; sp += red[w][2]; spp += red[w][3]; }
        double mc = sc / NN, ms = ss / NN;
        order_out[0] = (float)sqrt(mc * mc + ms * ms);
        double var = (spp - sp * sp / NN) / (NN - 1);
        if (var < 0) var = 0;
        coh_out[0] = (float)(1.0 / (1.0 + sqrt(var)));
    }
}

extern "C" void kernel_launch(void* const* d_in, const int* in_sizes, int n_in,
                              void* d_out, int out_size, void* d_ws, size_t ws_size,
                              hipStream_t stream) {
    const float* x    = (const float*)d_in[0];
    const float* A    = (const float*)d_in[1];
    const float* fw1  = (const float*)d_in[2];
    const float* fb1  = (const float*)d_in[3];
    const float* flng = (const float*)d_in[4];
    const float* flnb = (const float*)d_in[5];
    const float* fw2  = (const float*)d_in[6];
    const float* fb2  = (const float*)d_in[7];
    const float* fw3  = (const float*)d_in[8];
    const float* fb3  = (const float*)d_in[9];
    const float* cw1  = (const float*)d_in[10];
    const float* cb1  = (const float*)d_in[11];
    const float* cw2  = (const float*)d_in[12];
    const float* cb2  = (const float*)d_in[13];
    const float* sw1  = (const float*)d_in[14];
    const float* sb1  = (const float*)d_in[15];
    const float* slng = (const float*)d_in[16];
    const float* slnb = (const float*)d_in[17];
    const float* sw2  = (const float*)d_in[18];
    const float* sb2  = (const float*)d_in[19];
    const float* sw3  = (const float*)d_in[20];
    const float* sb3  = (const float*)d_in[21];
    const float* gcp  = (const float*)d_in[22];

    float* out    = (float*)d_out;
    float* desync = out;                    // 8192
    float* order  = out + 8192;             // 1
    float* phases = out + 8193;             // 8192
    float* freqo  = out + 16385;            // 8192
    float* coupo  = out + 24577;            // 8192
    float* synco  = out + 32769;            // 8192*260
    float* coh    = out + 2162689;          // 1

    char* wsb = (char*)d_ws;
    float*  cs   = (float*)(wsb + 0);        // 32 KB
    float*  pcAf = (float*)(wsb + 32768);    // fp32 fallback buffers
    float*  psAf = (float*)(wsb + 65536);
    float*  pcBf = (float*)(wsb + 98304);
    float*  psBf = (float*)(wsb + 131072);
    __half* pcAh = (__half*)(wsb + 163840);  // 16 KB
    __half* psAh = (__half*)(wsb + 180224);
    __half* pcBh = (__half*)(wsb + 196608);
    __half* psBh = (__half*)(wsb + 212992);
    unsigned char* Ap = (unsigned char*)(wsb + 262144);  // 96 MiB packed

    const bool usepack = ws_size >= (size_t)262144 + (size_t)NN * ROWB;

    if (usepack) {
        convert_pack_kernel<<<NN * 4, 256, 0, stream>>>(A, Ap);
    }
    pre_kernel<<<NN / RPB, 256, 0, stream>>>(x, fw1, fb1, flng, flnb, fw2, fb2, fw3, fb3,
                                             cw1, cb1, cw2, cb2, gcp,
                                             freqo, coupo, cs, phases,
                                             pcAf, psAf, pcAh, psAh);
    if (usepack) {
        for (int t = 0; t < 60; ++t) {
            const __half* pin  = (t & 1) ? pcBh : pcAh;
            const __half* sin_ = (t & 1) ? psBh : psAh;
            __half* pout = (t & 1) ? pcAh : pcBh;
            __half* sout = (t & 1) ? psAh : psBh;
            step_kernel_p<<<NN / SROWS, 256, 0, stream>>>(Ap, pin, sin_, freqo, cs, phases, pout, sout);
        }
    } else {
        for (int t = 0; t < 60; ++t) {
            const float* pin  = (t & 1) ? pcBf : pcAf;
            const float* sin_ = (t & 1) ? psBf : psAf;
            float* pout = (t & 1) ? pcAf : pcBf;
            float* sout = (t & 1) ? psAf : psBf;
            step_kernel<<<NN / SROWS, 256, 0, stream>>>(A, pin, sin_, freqo, cs, phases, pout, sout);
        }
    }
    post_kernel<<<NN / RPB, 256, 0, stream>>>(x, phases, sw1, sb1, slng, slnb, sw2, sb2, sw3, sb3,
                                              synco, desync);
    reduce_kernel<<<1, 1024, 0, stream>>>(phases, order, coh);
}

// Round 4
// 1466.309 us; speedup vs baseline: 1.9962x; 1.0137x over previous
//
#include <hip/hip_runtime.h>
#include <hip/hip_bf16.h>
#include <math.h>

#define NN 8192
#define DD 256
#define HH 128
#define RPB 16
#define DT_F 0.01f
#define TWO_PI_F 6.28318530717958647692f
#define ROWB 12288   // packed bytes per row: 8192 low-byte + 4096 high-nibble

__device__ __forceinline__ float gelu_exact(float t) {
    return 0.5f * t * (1.f + erff(t * 0.70710678118654752440f));
}
__device__ __forceinline__ float sigmoidf(float t) {
    return 1.f / (1.f + expf(-t));
}

// ---------------- A fp32 -> packed 12-bit conversion (permuted layout) ------
// Row element order is permuted: group g = it*64 + lane (512 groups of 16),
// element(it,lane,j,m) = 4*lane + 1024*it + 256*j + m   (j,m in 0..3)
// lo plane: uint4 per group (byte b=4j+m = low 8 bits of q_b)
// nib plane: uint2 per group (nibble k of word0 = q_k>>8 for b=k<8; word1 b=8+k)
__global__ __launch_bounds__(512) void convert_pack_kernel(
    const float* __restrict__ A, unsigned char* __restrict__ Ap)
{
    const int row = blockIdx.x;
    const int g = threadIdx.x;
    const int lane = g & 63, itq = g >> 6;
    const float* src = A + (size_t)row * NN + 4 * lane + 1024 * itq;
    unsigned q[16];
#pragma unroll
    for (int j = 0; j < 4; ++j) {
        float4 f = *(const float4*)(src + 256 * j);
        float v[4] = {f.x, f.y, f.z, f.w};
#pragma unroll
        for (int m = 0; m < 4; ++m) {
            float c = fminf(fmaxf(v[m], 0.f), 1.f);
            q[4 * j + m] = (unsigned)__float2int_rn(c * 4095.f);
        }
    }
    uint4 lo;
    lo.x = (q[0] & 0xFF) | ((q[1] & 0xFF) << 8) | ((q[2] & 0xFF) << 16) | ((q[3] & 0xFF) << 24);
    lo.y = (q[4] & 0xFF) | ((q[5] & 0xFF) << 8) | ((q[6] & 0xFF) << 16) | ((q[7] & 0xFF) << 24);
    lo.z = (q[8] & 0xFF) | ((q[9] & 0xFF) << 8) | ((q[10] & 0xFF) << 16) | ((q[11] & 0xFF) << 24);
    lo.w = (q[12] & 0xFF) | ((q[13] & 0xFF) << 8) | ((q[14] & 0xFF) << 16) | ((q[15] & 0xFF) << 24);
    uint2 nb;
    nb.x = (q[0] >> 8) | ((q[1] >> 8) << 4) | ((q[2] >> 8) << 8) | ((q[3] >> 8) << 12)
         | ((q[4] >> 8) << 16) | ((q[5] >> 8) << 20) | ((q[6] >> 8) << 24) | ((q[7] >> 8) << 28);
    nb.y = (q[8] >> 8) | ((q[9] >> 8) << 4) | ((q[10] >> 8) << 8) | ((q[11] >> 8) << 12)
         | ((q[12] >> 8) << 16) | ((q[13] >> 8) << 20) | ((q[14] >> 8) << 24) | ((q[15] >> 8) << 28);
    unsigned char* rowp = Ap + (size_t)row * ROWB;
    ((uint4*)rowp)[g] = lo;
    ((uint2*)(rowp + 8192))[g] = nb;
}

// ---------------- pre: frequencies, coupling, phases0, cos/sin snapshot ----
__global__ __launch_bounds__(256) void pre_kernel(
    const float* __restrict__ x,
    const float* __restrict__ fw1, const float* __restrict__ fb1,
    const float* __restrict__ flng, const float* __restrict__ flnb,
    const float* __restrict__ fw2, const float* __restrict__ fb2,
    const float* __restrict__ fw3, const float* __restrict__ fb3,
    const float* __restrict__ cw1, const float* __restrict__ cb1,
    const float* __restrict__ cw2, const float* __restrict__ cb2,
    const float* __restrict__ gcp,
    float* __restrict__ freq_out, float* __restrict__ coup_out,
    float* __restrict__ cs_ws, float* __restrict__ phases_out,
    float* __restrict__ pc0f, float* __restrict__ ps0f)
{
    __shared__ float xs[RPB][DD];
    __shared__ float h1[RPB][DD];
    __shared__ float h2[RPB][HH];
    __shared__ float hc[RPB][HH];
    const int tid = threadIdx.x;
    const int base_row = blockIdx.x * RPB;

    // load x tile
    {
        const float4* xg = (const float4*)(x + (size_t)base_row * DD);
        float4* xv = (float4*)&xs[0][0];
        for (int i = tid; i < RPB * DD / 4; i += 256) xv[i] = xg[i];
    }
    __syncthreads();

    // h1 = x @ fw1 + fb1
    {
        float acc[RPB];
#pragma unroll
        for (int r = 0; r < RPB; ++r) acc[r] = 0.f;
        const int c = tid;
        for (int k = 0; k < DD; k += 4) {
            float w0 = fw1[(k + 0) * DD + c];
            float w1 = fw1[(k + 1) * DD + c];
            float w2 = fw1[(k + 2) * DD + c];
            float w3 = fw1[(k + 3) * DD + c];
#pragma unroll
            for (int r = 0; r < RPB; ++r) {
                float4 xv = *(const float4*)&xs[r][k];
                acc[r] += xv.x * w0 + xv.y * w1 + xv.z * w2 + xv.w * w3;
            }
        }
        float bb = fb1[c];
#pragma unroll
        for (int r = 0; r < RPB; ++r) h1[r][c] = acc[r] + bb;
    }
    __syncthreads();

    // LN + tanh per row (one wave per row)
    {
        const int wave = tid >> 6, lane = tid & 63;
        for (int r = wave; r < RPB; r += 4) {
            float v0 = h1[r][lane], v1 = h1[r][lane + 64], v2 = h1[r][lane + 128], v3 = h1[r][lane + 192];
            float s = v0 + v1 + v2 + v3;
            for (int off = 32; off; off >>= 1) s += __shfl_xor(s, off);
            float m = s * (1.f / DD);
            float d0 = v0 - m, d1 = v1 - m, d2 = v2 - m, d3 = v3 - m;
            float q = d0 * d0 + d1 * d1 + d2 * d2 + d3 * d3;
            for (int off = 32; off; off >>= 1) q += __shfl_xor(q, off);
            float rstd = rsqrtf(q * (1.f / DD) + 1e-5f);
            h1[r][lane]       = tanhf(d0 * rstd * flng[lane]       + flnb[lane]);
            h1[r][lane + 64]  = tanhf(d1 * rstd * flng[lane + 64]  + flnb[lane + 64]);
            h1[r][lane + 128] = tanhf(d2 * rstd * flng[lane + 128] + flnb[lane + 128]);
            h1[r][lane + 192] = tanhf(d3 * rstd * flng[lane + 192] + flnb[lane + 192]);
        }
    }
    __syncthreads();

    // h2 = tanh(h1 @ fw2 + fb2)  [threads 0..127] ; hc = gelu(x @ cw1 + cb1) [threads 128..255]
    if (tid < HH) {
        const int c = tid;
        float acc[RPB];
#pragma unroll
        for (int r = 0; r < RPB; ++r) acc[r] = 0.f;
        for (int k = 0; k < DD; k += 4) {
            float w0 = fw2[(k + 0) * HH + c];
            float w1 = fw2[(k + 1) * HH + c];
            float w2 = fw2[(k + 2) * HH + c];
            float w3 = fw2[(k + 3) * HH + c];
#pragma unroll
            for (int r = 0; r < RPB; ++r) {
                float4 xv = *(const float4*)&h1[r][k];
                acc[r] += xv.x * w0 + xv.y * w1 + xv.z * w2 + xv.w * w3;
            }
        }
        float bb = fb2[c];
#pragma unroll
        for (int r = 0; r < RPB; ++r) h2[r][c] = tanhf(acc[r] + bb);
    } else {
        const int c = tid - HH;
        float acc[RPB];
#pragma unroll
        for (int r = 0; r < RPB; ++r) acc[r] = 0.f;
        for (int k = 0; k < DD; k += 4) {
            float w0 = cw1[(k + 0) * HH + c];
            float w1 = cw1[(k + 1) * HH + c];
            float w2 = cw1[(k + 2) * HH + c];
            float w3 = cw1[(k + 3) * HH + c];
#pragma unroll
            for (int r = 0; r < RPB; ++r) {
                float4 xv = *(const float4*)&xs[r][k];
                acc[r] += xv.x * w0 + xv.y * w1 + xv.z * w2 + xv.w * w3;
            }
        }
        float bb = cb1[c];
#pragma unroll
        for (int r = 0; r < RPB; ++r) {
            float t = acc[r] + bb;
            hc[r][c] = gelu_exact(t);
        }
    }
    __syncthreads();

    // freq / coupling / phases0 : one wave per row
    {
        const int wave = tid >> 6, lane = tid & 63;
        float gc = fminf(fmaxf(gcp[0], 0.1f), 2.0f);
        for (int r = wave; r < RPB; r += 4) {
            float f = h2[r][lane] * fw3[lane] + h2[r][lane + 64] * fw3[lane + 64];
            for (int off = 32; off; off >>= 1) f += __shfl_xor(f, off);
            float cpl = hc[r][lane] * cw2[lane] + hc[r][lane + 64] * cw2[lane + 64];
            for (int off = 32; off; off >>= 1) cpl += __shfl_xor(cpl, off);
            float ssum = 0.f, csum = 0.f;
#pragma unroll
            for (int j = 0; j < 4; ++j) {
                int idx = lane + 64 * j;
                float xv = xs[r][idx];
                float fi = (float)idx;
                ssum += xv * sinf(fi);
                csum += xv * cosf(fi);
            }
            for (int off = 32; off; off >>= 1) {
                ssum += __shfl_xor(ssum, off);
                csum += __shfl_xor(csum, off);
            }
            if (lane == 0) {
                int row = base_row + r;
                freq_out[row] = f + fb3[0];
                float sg = sigmoidf(cpl + cb2[0]);
                coup_out[row] = sg;
                cs_ws[row] = sg * gc;
                float ph = atan2f(ssum, csum);
                phases_out[row] = ph;
                pc0f[row] = cosf(ph);
                ps0f[row] = sinf(ph);
            }
        }
    }
}

// ---------------- 12-bit unpack: 4 elements of one lo-word ------------------
__device__ __forceinline__ void acc4(unsigned lo, unsigned he, unsigned ho, const int j0,
                                     float4 cv, float4 sv, float& ac, float& as) {
#if __has_builtin(__builtin_amdgcn_perm)
    unsigned u0 = __builtin_amdgcn_perm(he, lo, 0x0C0C0000u | ((4u + j0) << 8) | 0u);
    unsigned u1 = __builtin_amdgcn_perm(ho, lo, 0x0C0C0000u | ((4u + j0) << 8) | 1u);
    unsigned u2 = __builtin_amdgcn_perm(he, lo, 0x0C0C0000u | ((5u + j0) << 8) | 2u);
    unsigned u3 = __builtin_amdgcn_perm(ho, lo, 0x0C0C0000u | ((5u + j0) << 8) | 3u);
#else
    unsigned u0 = ((lo >> 0)  & 0xFFu) | (((he >> (8 * j0)) & 0xFFu) << 8);
    unsigned u1 = ((lo >> 8)  & 0xFFu) | (((ho >> (8 * j0)) & 0xFFu) << 8);
    unsigned u2 = ((lo >> 16) & 0xFFu) | (((he >> (8 * j0 + 8)) & 0xFFu) << 8);
    unsigned u3 = ((lo >> 24) & 0xFFu) | (((ho >> (8 * j0 + 8)) & 0xFFu) << 8);
#endif
    float f0 = (float)u0, f1 = (float)u1, f2 = (float)u2, f3 = (float)u3;
    ac = fmaf(f0, cv.x, ac); as = fmaf(f0, sv.x, as);
    ac = fmaf(f1, cv.y, ac); as = fmaf(f1, sv.y, as);
    ac = fmaf(f2, cv.z, ac); as = fmaf(f2, sv.z, as);
    ac = fmaf(f3, cv.w, ac); as = fmaf(f3, sv.w, as);
}

// ---------------- one Kuramoto step (12-bit packed A, f32 vectors) ----------
#define SROWS 16     // rows per block (8 waves x 2 rows)
__global__ __launch_bounds__(512) void step_kernel_p(
    const unsigned char* __restrict__ Ap,
    const float* __restrict__ pc_in, const float* __restrict__ ps_in,
    const float* __restrict__ freq, const float* __restrict__ cs,
    float* __restrict__ phases,
    float* __restrict__ pc_out, float* __restrict__ ps_out)
{
    __shared__ float pcs[NN];   // 32 KB
    __shared__ float pss[NN];   // 32 KB
    const int tid = threadIdx.x, lane = tid & 63, wave = tid >> 6;
    for (int i = tid; i < NN / 4; i += 512) {
        ((float4*)pcs)[i] = ((const float4*)pc_in)[i];
        ((float4*)pss)[i] = ((const float4*)ps_in)[i];
    }
    __syncthreads();

    const int row0 = blockIdx.x * SROWS + wave * 2;
    const uint4* lo0p = (const uint4*)(Ap + (size_t)(row0 + 0) * ROWB);
    const uint4* lo1p = (const uint4*)(Ap + (size_t)(row0 + 1) * ROWB);
    const uint2* nb0p = (const uint2*)(Ap + (size_t)(row0 + 0) * ROWB + 8192);
    const uint2* nb1p = (const uint2*)(Ap + (size_t)(row0 + 1) * ROWB + 8192);
    const float4* Pc = (const float4*)pcs;
    const float4* Ps = (const float4*)pss;

    float lac0 = 0.f, las0 = 0.f, lac1 = 0.f, las1 = 0.f;
#pragma unroll 2
    for (int it = 0; it < 8; ++it) {
        const int gidx = it * 64 + lane;
        uint4 lo0 = lo0p[gidx];
        uint4 lo1 = lo1p[gidx];
        uint2 nb0 = nb0p[gidx];
        uint2 nb1 = nb1p[gidx];
        const int base = lane + 256 * it;
        float4 c0 = Pc[base], c1 = Pc[base + 64], c2 = Pc[base + 128], c3 = Pc[base + 192];
        float4 s0 = Ps[base], s1 = Ps[base + 64], s2 = Ps[base + 128], s3 = Ps[base + 192];

        unsigned he0a = nb0.x & 0x0F0F0F0Fu, ho0a = (nb0.x >> 4) & 0x0F0F0F0Fu;
        unsigned he0b = nb0.y & 0x0F0F0F0Fu, ho0b = (nb0.y >> 4) & 0x0F0F0F0Fu;
        unsigned he1a = nb1.x & 0x0F0F0F0Fu, ho1a = (nb1.x >> 4) & 0x0F0F0F0Fu;
        unsigned he1b = nb1.y & 0x0F0F0F0Fu, ho1b = (nb1.y >> 4) & 0x0F0F0F0Fu;

        acc4(lo0.x, he0a, ho0a, 0, c0, s0, lac0, las0);
        acc4(lo1.x, he1a, ho1a, 0, c0, s0, lac1, las1);
        acc4(lo0.y, he0a, ho0a, 2, c1, s1, lac0, las0);
        acc4(lo1.y, he1a, ho1a, 2, c1, s1, lac1, las1);
        acc4(lo0.z, he0b, ho0b, 0, c2, s2, lac0, las0);
        acc4(lo1.z, he1b, ho1b, 0, c2, s2, lac1, las1);
        acc4(lo0.w, he0b, ho0b, 2, c3, s3, lac0, las0);
        acc4(lo1.w, he1b, ho1b, 2, c3, s3, lac1, las1);
    }
    for (int off = 32; off; off >>= 1) {
        lac0 += __shfl_xor(lac0, off);
        las0 += __shfl_xor(las0, off);
        lac1 += __shfl_xor(lac1, off);
        las1 += __shfl_xor(las1, off);
    }
    if (lane == 0) {
        const float inv = 1.f / 4095.f;
#pragma unroll
        for (int rr = 0; rr < 2; ++rr) {
            const int row = row0 + rr;
            float c = (rr ? lac1 : lac0) * inv;
            float s = (rr ? las1 : las0) * inv;
            float ph = phases[row];
            float ce = atan2f(s, c + 1e-8f) - ph;
            float dphi = freq[row] + cs[row] * sinf(ce);
            float pn = ph + DT_F * dphi;
            pn = fmodf(pn, TWO_PI_F);
            if (pn < 0.f) pn += TWO_PI_F;
            phases[row] = pn;
            pc_out[row] = cosf(pn);
            ps_out[row] = sinf(pn);
        }
    }
}

// ---------------- fp32 fallback step (if ws too small for packed A) --------
#define FSROWS 8
#define CHUNK 4096
__global__ __launch_bounds__(256) void step_kernel(
    const float* __restrict__ A,
    const float* __restrict__ pc_in, const float* __restrict__ ps_in,
    const float* __restrict__ freq, const float* __restrict__ cs,
    float* __restrict__ phases,
    float* __restrict__ pc_out, float* __restrict__ ps_out)
{
    __shared__ float pcs[CHUNK];
    __shared__ float pss[CHUNK];
    const int tid = threadIdx.x, lane = tid & 63, wave = tid >> 6;
    const int row0 = blockIdx.x * FSROWS + wave * (FSROWS / 4);
    float accC[FSROWS / 4], accS[FSROWS / 4];
#pragma unroll
    for (int rr = 0; rr < FSROWS / 4; ++rr) { accC[rr] = 0.f; accS[rr] = 0.f; }

    for (int ch = 0; ch < NN / CHUNK; ++ch) {
        const float4* pcg = (const float4*)(pc_in + ch * CHUNK);
        const float4* psg = (const float4*)(ps_in + ch * CHUNK);
        for (int i = tid; i < CHUNK / 4; i += 256) {
            ((float4*)pcs)[i] = pcg[i];
            ((float4*)pss)[i] = psg[i];
        }
        __syncthreads();
#pragma unroll
        for (int rr = 0; rr < FSROWS / 4; ++rr) {
            const float4* Ar = (const float4*)(A + (size_t)(row0 + rr) * NN + ch * CHUNK);
            float lac = 0.f, las = 0.f;
#pragma unroll 4
            for (int it = 0; it < CHUNK / 256; ++it) {
                int c4 = it * 64 + lane;
                float4 a = Ar[c4];
                float4 c = ((const float4*)pcs)[c4];
                float4 s = ((const float4*)pss)[c4];
                lac += a.x * c.x + a.y * c.y + a.z * c.z + a.w * c.w;
                las += a.x * s.x + a.y * s.y + a.z * s.z + a.w * s.w;
            }
            accC[rr] += lac;
            accS[rr] += las;
        }
        __syncthreads();
    }

#pragma unroll
    for (int rr = 0; rr < FSROWS / 4; ++rr) {
        float c = accC[rr], s = accS[rr];
        for (int off = 32; off; off >>= 1) {
            c += __shfl_xor(c, off);
            s += __shfl_xor(s, off);
        }
        if (lane == 0) {
            int row = row0 + rr;
            float ph = phases[row];
            float ce = atan2f(s, c + 1e-8f) - ph;
            float dphi = freq[row] + cs[row] * sinf(ce);
            float pn = ph + DT_F * dphi;
            pn = fmodf(pn, TWO_PI_F);
            if (pn < 0.f) pn += TWO_PI_F;
            phases[row] = pn;
            pc_out[row] = cosf(pn);
            ps_out[row] = sinf(pn);
        }
    }
}

// ---------------- post: sync_input, sync MLP -> desync ----------------------
#define SD 260
#define SDP 264
__global__ __launch_bounds__(256) void post_kernel(
    const float* __restrict__ x, const float* __restrict__ phases,
    const float* __restrict__ sw1, const float* __restrict__ sb1,
    const float* __restrict__ slng, const float* __restrict__ slnb,
    const float* __restrict__ sw2, const float* __restrict__ sb2,
    const float* __restrict__ sw3, const float* __restrict__ sb3,
    float* __restrict__ sync_out, float* __restrict__ desync_out)
{
    __shared__ float xs[RPB][SDP];
    __shared__ float h1[RPB][DD];
    __shared__ float h2[RPB][HH];
    const int tid = threadIdx.x;
    const int base_row = blockIdx.x * RPB;

    // load x tile
    for (int i = tid; i < RPB * DD / 4; i += 256) {
        int r = i / (DD / 4), c4 = i % (DD / 4);
        *(float4*)&xs[r][c4 * 4] = ((const float4*)(x + (size_t)(base_row + r) * DD))[c4];
    }
    if (tid < RPB) {
        float p = phases[base_row + tid];
        xs[tid][256] = cosf(p);
        xs[tid][257] = sinf(p);
        xs[tid][258] = cosf(2.f * p);
        xs[tid][259] = sinf(2.f * p);
    }
    __syncthreads();

    // write sync_input
    for (int i = tid; i < RPB * SD; i += 256) {
        int r = i / SD, c = i % SD;
        sync_out[(size_t)(base_row + r) * SD + c] = xs[r][c];
    }

    // h1 = sync_input @ sw1 + sb1
    {
        float acc[RPB];
#pragma unroll
        for (int r = 0; r < RPB; ++r) acc[r] = 0.f;
        const int c = tid;
        for (int k = 0; k < SD; k += 4) {
            float w0 = sw1[(k + 0) * DD + c];
            float w1 = sw1[(k + 1) * DD + c];
            float w2 = sw1[(k + 2) * DD + c];
            float w3 = sw1[(k + 3) * DD + c];
#pragma unroll
            for (int r = 0; r < RPB; ++r) {
                float4 xv = *(const float4*)&xs[r][k];
                acc[r] += xv.x * w0 + xv.y * w1 + xv.z * w2 + xv.w * w3;
            }
        }
        float bb = sb1[c];
#pragma unroll
        for (int r = 0; r < RPB; ++r) h1[r][c] = acc[r] + bb;
    }
    __syncthreads();

    // LN + GELU per row
    {
        const int wave = tid >> 6, lane = tid & 63;
        for (int r = wave; r < RPB; r += 4) {
            float v0 = h1[r][lane], v1 = h1[r][lane + 64], v2 = h1[r][lane + 128], v3 = h1[r][lane + 192];
            float s = v0 + v1 + v2 + v3;
            for (int off = 32; off; off >>= 1) s += __shfl_xor(s, off);
            float m = s * (1.f / DD);
            float d0 = v0 - m, d1 = v1 - m, d2 = v2 - m, d3 = v3 - m;
            float q = d0 * d0 + d1 * d1 + d2 * d2 + d3 * d3;
            for (int off = 32; off; off >>= 1) q += __shfl_xor(q, off);
            float rstd = rsqrtf(q * (1.f / DD) + 1e-5f);
            h1[r][lane]       = gelu_exact(d0 * rstd * slng[lane]       + slnb[lane]);
            h1[r][lane + 64]  = gelu_exact(d1 * rstd * slng[lane + 64]  + slnb[lane + 64]);
            h1[r][lane + 128] = gelu_exact(d2 * rstd * slng[lane + 128] + slnb[lane + 128]);
            h1[r][lane + 192] = gelu_exact(d3 * rstd * slng[lane + 192] + slnb[lane + 192]);
        }
    }
    __syncthreads();

    // h2 = gelu(h1 @ sw2 + sb2)  [threads 0..127]
    if (tid < HH) {
        const int c = tid;
        float acc[RPB];
#pragma unroll
        for (int r = 0; r < RPB; ++r) acc[r] = 0.f;
        for (int k = 0; k < DD; k += 4) {
            float w0 = sw2[(k + 0) * HH + c];
            float w1 = sw2[(k + 1) * HH + c];
            float w2 = sw2[(k + 2) * HH + c];
            float w3 = sw2[(k + 3) * HH + c];
#pragma unroll
            for (int r = 0; r < RPB; ++r) {
                float4 xv = *(const float4*)&h1[r][k];
                acc[r] += xv.x * w0 + xv.y * w1 + xv.z * w2 + xv.w * w3;
            }
        }
        float bb = sb2[c];
#pragma unroll
        for (int r = 0; r < RPB; ++r) h2[r][c] = gelu_exact(acc[r] + bb);
    }
    __syncthreads();

    // desync = sigmoid(h2 @ sw3 + sb3) : one wave per row
    {
        const int wave = tid >> 6, lane = tid & 63;
        for (int r = wave; r < RPB; r += 4) {
            float t = h2[r][lane] * sw3[lane] + h2[r][lane + 64] * sw3[lane + 64];
            for (int off = 32; off; off >>= 1) t += __shfl_xor(t, off);
            if (lane == 0) desync_out[base_row + r] = sigmoidf(t + sb3[0]);
        }
    }
}

// ---------------- global scalar reductions ---------------------------------
__global__ __launch_bounds__(1024) void reduce_kernel(
    const float* __restrict__ phases,
    float* __restrict__ order_out, float* __restrict__ coh_out)
{
    __shared__ double red[16][4];
    const int tid = threadIdx.x;
    double sc = 0, ss = 0, sp = 0, spp = 0;
    for (int i = tid; i < NN; i += 1024) {
        float p = phases[i];
        sc += (double)cosf(p);
        ss += (double)sinf(p);
        sp += (double)p;
        spp += (double)p * (double)p;
    }
    const int lane = tid & 63, wave = tid >> 6;
    for (int off = 32; off; off >>= 1) {
        sc += __shfl_xor(sc, off);
        ss += __shfl_xor(ss, off);
        sp += __shfl_xor(sp, off);
        spp += __shfl_xor(spp, off);
    }
    if (lane == 0) { red[wave][0] = sc; red[wave][1] = ss; red[wave][2] = sp; red[wave][3] = spp; }
    __syncthreads();
    if (tid == 0) {
        sc = 0; ss = 0; sp = 0; spp = 0;
        for (int w = 0; w < 16; ++w) { sc += red[w][0]; ss += red[w][1]; sp += red[w][2]; spp += red[w][3]; }
        double mc = sc / NN, ms = ss / NN;
        order_out[0] = (float)sqrt(mc * mc + ms * ms);
        double var = (spp - sp * sp / NN) / (NN - 1);
        if (var < 0) var = 0;
        coh_out[0] = (float)(1.0 / (1.0 + sqrt(var)));
    }
}

extern "C" void kernel_launch(void* const* d_in, const int* in_sizes, int n_in,
                              void* d_out, int out_size, void* d_ws, size_t ws_size,
                              hipStream_t stream) {
    const float* x    = (const float*)d_in[0];
    const float* A    = (const float*)d_in[1];
    const float* fw1  = (const float*)d_in[2];
    const float* fb1  = (const float*)d_in[3];
    const float* flng = (const float*)d_in[4];
    const float* flnb = (const float*)d_in[5];
    const float* fw2  = (const float*)d_in[6];
    const float* fb2  = (const float*)d_in[7];
    const float* fw3  = (const float*)d_in[8];
    const float* fb3  = (const float*)d_in[9];
    const float* cw1  = (const float*)d_in[10];
    const float* cb1  = (const float*)d_in[11];
    const float* cw2  = (const float*)d_in[12];
    const float* cb2  = (const float*)d_in[13];
    const float* sw1  = (const float*)d_in[14];
    const float* sb1  = (const float*)d_in[15];
    const float* slng = (const float*)d_in[16];
    const float* slnb = (const float*)d_in[17];
    const float* sw2  = (const float*)d_in[18];
    const float* sb2  = (const float*)d_in[19];
    const float* sw3  = (const float*)d_in[20];
    const float* sb3  = (const float*)d_in[21];
    const float* gcp  = (const float*)d_in[22];

    float* out    = (float*)d_out;
    float* desync = out;                    // 8192
    float* order  = out + 8192;             // 1
    float* phases = out + 8193;             // 8192
    float* freqo  = out + 16385;            // 8192
    float* coupo  = out + 24577;            // 8192
    float* synco  = out + 32769;            // 8192*260
    float* coh    = out + 2162689;          // 1

    char* wsb = (char*)d_ws;
    float*  cs   = (float*)(wsb + 0);        // 32 KB
    float*  pcA  = (float*)(wsb + 32768);    // 32 KB each
    float*  psA  = (float*)(wsb + 65536);
    float*  pcB  = (float*)(wsb + 98304);
    float*  psB  = (float*)(wsb + 131072);
    unsigned char* Ap = (unsigned char*)(wsb + 262144);  // 96 MiB packed

    const bool usepack = ws_size >= (size_t)262144 + (size_t)NN * ROWB;

    if (usepack) {
        convert_pack_kernel<<<NN, 512, 0, stream>>>(A, Ap);
    }
    pre_kernel<<<NN / RPB, 256, 0, stream>>>(x, fw1, fb1, flng, flnb, fw2, fb2, fw3, fb3,
                                             cw1, cb1, cw2, cb2, gcp,
                                             freqo, coupo, cs, phases, pcA, psA);
    if (usepack) {
        for (int t = 0; t < 60; ++t) {
            const float* pin  = (t & 1) ? pcB : pcA;
            const float* sin_ = (t & 1) ? psB : psA;
            float* pout = (t & 1) ? pcA : pcB;
            float* sout = (t & 1) ? psA : psB;
            step_kernel_p<<<NN / SROWS, 512, 0, stream>>>(Ap, pin, sin_, freqo, cs, phases, pout, sout);
        }
    } else {
        for (int t = 0; t < 60; ++t) {
            const float* pin  = (t & 1) ? pcB : pcA;
            const float* sin_ = (t & 1) ? psB : psA;
            float* pout = (t & 1) ? pcA : pcB;
            float* sout = (t & 1) ? psA : psB;
            step_kernel<<<NN / FSROWS, 256, 0, stream>>>(A, pin, sin_, freqo, cs, phases, pout, sout);
        }
    }
    post_kernel<<<NN / RPB, 256, 0, stream>>>(x, phases, sw1, sb1, slng, slnb, sw2, sb2, sw3, sb3,
                                              synco, desync);
    reduce_kernel<<<1, 1024, 0, stream>>>(phases, order, coh);
}